// Round 12
// baseline (70.264 us; speedup 1.0000x reference)
//
#include <hip/hip_runtime.h>
#include <math.h>

#define TT 2048
#define NH 8
#define HDD 64
#define CL 32          // chunk length
#define NC 64          // number of chunks
#define EPS_F 1e-8f

typedef __attribute__((ext_vector_type(8))) _Float16 half8;
typedef __attribute__((ext_vector_type(4))) _Float16 half4;
typedef __attribute__((ext_vector_type(4))) float    f32x4;

__device__ __forceinline__ unsigned int pack2h(float a, float b) {
    union { _Float16 h[2]; unsigned int u; } z;
    z.h[0] = (_Float16)a; z.h[1] = (_Float16)b; return z.u;
}
__device__ __forceinline__ float2 unpack2h(unsigned int w) {
    union { unsigned int u; _Float16 h[2]; } z; z.u = w;
    return make_float2((float)z.h[0], (float)z.h[1]);
}
// register-level negate: XOR fp16 sign bits
__device__ __forceinline__ half8 neg8r(half8 v) {
    union { half8 h; unsigned int u[4]; } z; z.h = v;
    #pragma unroll
    for (int i = 0; i < 4; ++i) z.u[i] ^= 0x80008000u;
    return z.h;
}
__device__ __forceinline__ half8 cvt8f(float4 a, float4 b) {
    half8 r;
    r[0]=(_Float16)a.x; r[1]=(_Float16)a.y; r[2]=(_Float16)a.z; r[3]=(_Float16)a.w;
    r[4]=(_Float16)b.x; r[5]=(_Float16)b.y; r[6]=(_Float16)b.z; r[7]=(_Float16)b.w;
    return r;
}

// ---------------------------------------------------------------------------
// prep: fused wconv (blocks 0..383) + w2prep (384..639) + biasprep (640..655)
// W2T rows permuted to OUTPUT-INTERLEAVED order: o = n<512 ? 2n : 2(n-512)+1,
// so GEMM2's epilogue writes are contiguous fp32 (no stride-2 scatter).
// ---------------------------------------------------------------------------
__global__ __launch_bounds__(256) void prep_kernel(
    const float* __restrict__ q_wr, const float* __restrict__ q_wi,
    const float* __restrict__ k_wr, const float* __restrict__ k_wi,
    const float* __restrict__ v_wr, const float* __restrict__ v_wi,
    const float* __restrict__ o_wr, const float* __restrict__ o_wi,
    const float* __restrict__ bq_r, const float* __restrict__ bq_i,
    const float* __restrict__ bk_r, const float* __restrict__ bk_i,
    const float* __restrict__ bv_r, const float* __restrict__ bv_i,
    const float* __restrict__ o_br, const float* __restrict__ o_bi,
    _Float16* __restrict__ WT, _Float16* __restrict__ W2T,
    float* __restrict__ ball, float* __restrict__ b2a)
{
    __shared__ float tile[64][65];
    const int bid = blockIdx.x, tid = threadIdx.x;
    if (bid < 384) {
        const int z = bid >> 6, t = bid & 63;       // z in 0..5
        const int k0 = (t >> 3) * 64, n0 = (t & 7) * 64;
        const int g = z >> 1, p = z & 1;
        const float* W;
        switch (z) {
          case 0: W = q_wr; break;
          case 1: W = q_wi; break;
          case 2: W = k_wr; break;
          case 3: W = k_wi; break;
          case 4: W = v_wr; break;
          default: W = v_wi; break;                 // z == 5
        }
        #pragma unroll
        for (int it = 0; it < 16; ++it) {
            int idx = it * 256 + tid;
            tile[idx >> 6][idx & 63] = W[(size_t)(k0 + (idx >> 6)) * 512 + n0 + (idx & 63)];
        }
        __syncthreads();
        #pragma unroll
        for (int it = 0; it < 16; ++it) {
            int idx = it * 256 + tid;
            int nr = idx >> 6, kc = idx & 63;
            int n = n0 + nr;
            int R = g * 1024 + ((n >> 4) << 5) + p * 16 + (n & 15);
            WT[(size_t)R * 512 + k0 + kc] = (_Float16)tile[kc][nr];
        }
    } else if (bid < 640) {
        const int t = bid - 384;
        const int i0 = (t >> 4) * 64, j0 = (t & 15) * 64;
        const float* src; float sgn; int io, jo;
        if (i0 < 512) {
            if (j0 < 512) { src = o_wr; sgn = 1.f;  io = i0; jo = j0; }
            else          { src = o_wi; sgn = 1.f;  io = i0; jo = j0 - 512; }
        } else {
            if (j0 < 512) { src = o_wi; sgn = -1.f; io = i0 - 512; jo = j0; }
            else          { src = o_wr; sgn = 1.f;  io = i0 - 512; jo = j0 - 512; }
        }
        #pragma unroll
        for (int it = 0; it < 16; ++it) {
            int idx = it * 256 + tid;
            tile[idx >> 6][idx & 63] = sgn * src[(size_t)(io + (idx >> 6)) * 512 + jo + (idx & 63)];
        }
        __syncthreads();
        #pragma unroll
        for (int it = 0; it < 16; ++it) {
            int idx = it * 256 + tid;
            int nr = idx >> 6, kc = idx & 63;
            int n = j0 + nr;
            int o = (n < 512) ? (2 * n) : (2 * (n - 512) + 1);   // interleave
            W2T[(size_t)o * 1024 + i0 + kc] = (_Float16)tile[kc][nr];
        }
    } else {
        int idx = (bid - 640) * 256 + tid;   // 0..4095
        if (idx < 3072) {
            int g = idx >> 10, wq = idx & 1023;
            int p = (wq >> 4) & 1;
            int n = ((wq >> 5) << 4) | (wq & 15);
            float v;
            switch (g * 2 + p) {
              case 0: v = bq_r[n]; break;
              case 1: v = bq_i[n]; break;
              case 2: v = bk_r[n]; break;
              case 3: v = bk_i[n]; break;
              case 4: v = bv_r[n]; break;
              default: v = bv_i[n]; break;
            }
            ball[idx] = v;
        } else {
            int j = idx - 3072;
            float v = (j < 512) ? o_br[j] : o_bi[j - 512];
            int o = (j < 512) ? (2 * j) : (2 * (j - 512) + 1);   // interleave
            b2a[o] = v;
        }
    }
}

// ---------------------------------------------------------------------------
// GEMM1 fused w/ feature epilogue. BM=64, double-buffered LDS, 1 barrier/step.
// Epilogue: LDS-transpose-staged per-plane stores -> fully coalesced 128B rows.
// grid (24 n-tiles, 32 m-tiles)
// ---------------------------------------------------------------------------
__global__ __launch_bounds__(256) void gemm_qkv_kernel(
    const float* __restrict__ X,
    const _Float16* __restrict__ BT,
    const float* __restrict__ ball,
    _Float16* __restrict__ PL)
{
    __shared__ _Float16 sA[2][64 * 32];
    __shared__ _Float16 sB[2][128 * 32];
    const int tid = threadIdx.x;
    const int bx = blockIdx.x, by = blockIdx.y;
    const int m0 = by * 64, R0 = bx * 128;
    const int g = bx >> 3;
    const int nb = (bx & 7) * 64;
    const int lane = tid & 63;
    const int w = tid >> 6, wm = w >> 1, wn = w & 1;
    const int quad = lane >> 4, l15 = lane & 15;

    f32x4 acc[2][4];
    #pragma unroll
    for (int i = 0; i < 2; ++i)
        #pragma unroll
        for (int j = 0; j < 4; ++j) { f32x4 z = {0.f, 0.f, 0.f, 0.f}; acc[i][j] = z; }

    const int rA0 = tid >> 2, sq = tid & 3;
    const float* gA0 = X + (size_t)(m0 + rA0) * 512 + (sq ^ ((rA0 >> 1) & 3)) * 8;
    const int aofs = rA0 * 32 + sq * 8;

    const int rB0 = tid >> 2, rB1 = rB0 + 64;
    const _Float16* gB0 = BT + (size_t)(R0 + rB0) * 512 + (sq ^ ((rB0 >> 1) & 3)) * 8;
    const _Float16* gB1 = BT + (size_t)(R0 + rB1) * 512 + (sq ^ ((rB1 >> 1) & 3)) * 8;
    const int bofs0 = rB0 * 32 + sq * 8;
    const int bofs1 = rB1 * 32 + sq * 8;

    const int arow = wm * 32 + l15;
    const int brow = wn * 64 + l15;

    float4 a00 = *(const float4*)gA0, a01 = *(const float4*)(gA0 + 4);
    float4 pb0 = *(const float4*)gB0, pb1 = *(const float4*)gB1;
    *(half8*)&sA[0][aofs]  = cvt8f(a00, a01);
    *(float4*)&sB[0][bofs0] = pb0;
    *(float4*)&sB[0][bofs1] = pb1;
    a00 = *(const float4*)(gA0 + 32); a01 = *(const float4*)(gA0 + 36);
    pb0 = *(const float4*)(gB0 + 32); pb1 = *(const float4*)(gB1 + 32);
    __syncthreads();

    for (int ks = 0; ks < 16; ++ks) {
        const int cur = ks & 1;
        half8 af[2], bf[4];
        #pragma unroll
        for (int mt = 0; mt < 2; ++mt) {
            int r = arow + mt * 16;
            int qp = quad ^ ((r >> 1) & 3);
            af[mt] = *(half8*)&sA[cur][r * 32 + qp * 8];
        }
        #pragma unroll
        for (int nt = 0; nt < 4; ++nt) {
            int r = brow + nt * 16;
            int qp = quad ^ ((r >> 1) & 3);
            bf[nt] = *(half8*)&sB[cur][r * 32 + qp * 8];
        }
        #pragma unroll
        for (int mt = 0; mt < 2; ++mt)
            #pragma unroll
            for (int nt = 0; nt < 4; ++nt)
                acc[mt][nt] = __builtin_amdgcn_mfma_f32_16x16x32_f16(af[mt], bf[nt], acc[mt][nt], 0, 0, 0);
        if (ks + 1 < 16) {
            *(half8*)&sA[cur ^ 1][aofs]  = cvt8f(a00, a01);
            *(float4*)&sB[cur ^ 1][bofs0] = pb0;
            *(float4*)&sB[cur ^ 1][bofs1] = pb1;
            if (ks + 2 < 16) {
                int ko = (ks + 2) << 5;
                a00 = *(const float4*)(gA0 + ko); a01 = *(const float4*)(gA0 + ko + 4);
                pb0 = *(const float4*)(gB0 + ko); pb1 = *(const float4*)(gB1 + ko);
            }
        }
        __syncthreads();
    }

    // ---- epilogue: stage 64x64 plane tiles through LDS, coalesced store ----
    _Float16* tileT = &sB[0][0];            // reuse (dead after K-loop): 64x68
    const int trow = tid >> 2, tseg = tid & 3;
    float bre[2], bim[2];
    bre[0] = ball[R0 + wn * 64 + l15];
    bim[0] = ball[R0 + wn * 64 + 16 + l15];
    bre[1] = ball[R0 + wn * 64 + 32 + l15];
    bim[1] = ball[R0 + wn * 64 + 48 + l15];
    const int wrow0 = wm * 32 + quad * 4;
    const int wcol0 = wn * 32 + l15;

    const int nplanes = (g == 2) ? 2 : 3;
    for (int p = 0; p < nplanes; ++p) {
        #pragma unroll
        for (int j = 0; j < 2; ++j) {
            #pragma unroll
            for (int mt = 0; mt < 2; ++mt) {
                #pragma unroll
                for (int reg = 0; reg < 4; ++reg) {
                    float xr = acc[mt][2 * j][reg] + bre[j];
                    float xi = acc[mt][2 * j + 1][reg] + bim[j];
                    float val;
                    if (g == 2) {
                        val = (p == 0) ? xr : xi;
                    } else {
                        float gv = sqrtf(xr * xr + xi * xi);
                        float f = gv / (gv + EPS_F);
                        if (p == 0)      val = xr * f;
                        else if (p == 1) val = (g == 1) ? (-xi * f) : (xi * f);
                        else             val = gv;
                    }
                    tileT[(wrow0 + mt * 16 + reg) * 68 + wcol0 + j * 16] = (_Float16)val;
                }
            }
        }
        __syncthreads();
        int pidx = (g == 0) ? p : ((g == 1) ? 3 + p : 6 + p);
        _Float16* dst = PL + (size_t)pidx * 1048576 + (size_t)(m0 + trow) * 512 + nb + tseg * 16;
        half8 v0 = *(half8*)&tileT[trow * 68 + tseg * 16];
        half8 v1 = *(half8*)&tileT[trow * 68 + tseg * 16 + 8];
        *(half8*)&dst[0] = v0;
        *(half8*)&dst[8] = v1;
        __syncthreads();
    }
}

// ---------------------------------------------------------------------------
// GEMM2: out = Y2h @ W2T'^T + b2a (interleaved cols -> coalesced writes).
// BM=64, double-buffered, 1 barrier/step. grid (8, 32).
// ---------------------------------------------------------------------------
__global__ __launch_bounds__(256) void gemm_f16_kernel(
    const _Float16* __restrict__ A,
    const _Float16* __restrict__ BT,
    const float* __restrict__ bias,
    float* __restrict__ C,
    int K, int out_mode)
{
    __shared__ _Float16 sA[2][64 * 32];
    __shared__ _Float16 sB[2][128 * 32];
    const int tid = threadIdx.x;
    const int m0 = blockIdx.y * 64, n0 = blockIdx.x * 128;
    const int lane = tid & 63;
    const int w = tid >> 6, wm = w >> 1, wn = w & 1;
    const int quad = lane >> 4, l15 = lane & 15;

    f32x4 acc[2][4];
    #pragma unroll
    for (int i = 0; i < 2; ++i)
        #pragma unroll
        for (int j = 0; j < 4; ++j) { f32x4 z = {0.f, 0.f, 0.f, 0.f}; acc[i][j] = z; }

    const int rA0 = tid >> 2, sq = tid & 3;
    const _Float16* gA0 = A + (size_t)(m0 + rA0) * K + (sq ^ ((rA0 >> 1) & 3)) * 8;
    const int aofs = rA0 * 32 + sq * 8;

    const int rB0 = tid >> 2, rB1 = rB0 + 64;
    const _Float16* gB0 = BT + (size_t)(n0 + rB0) * K + (sq ^ ((rB0 >> 1) & 3)) * 8;
    const _Float16* gB1 = BT + (size_t)(n0 + rB1) * K + (sq ^ ((rB1 >> 1) & 3)) * 8;
    const int bofs0 = rB0 * 32 + sq * 8;
    const int bofs1 = rB1 * 32 + sq * 8;

    const int arow = wm * 32 + l15;
    const int brow = wn * 64 + l15;
    const int nsteps = K >> 5;

    float4 pa0 = *(const float4*)gA0;
    float4 pb0 = *(const float4*)gB0, pb1 = *(const float4*)gB1;
    *(float4*)&sA[0][aofs]  = pa0;
    *(float4*)&sB[0][bofs0] = pb0;
    *(float4*)&sB[0][bofs1] = pb1;
    if (nsteps > 1) {
        pa0 = *(const float4*)(gA0 + 32);
        pb0 = *(const float4*)(gB0 + 32); pb1 = *(const float4*)(gB1 + 32);
    }
    __syncthreads();

    for (int ks = 0; ks < nsteps; ++ks) {
        const int cur = ks & 1;
        half8 af[2], bf[4];
        #pragma unroll
        for (int mt = 0; mt < 2; ++mt) {
            int r = arow + mt * 16;
            int qp = quad ^ ((r >> 1) & 3);
            af[mt] = *(half8*)&sA[cur][r * 32 + qp * 8];
        }
        #pragma unroll
        for (int nt = 0; nt < 4; ++nt) {
            int r = brow + nt * 16;
            int qp = quad ^ ((r >> 1) & 3);
            bf[nt] = *(half8*)&sB[cur][r * 32 + qp * 8];
        }
        #pragma unroll
        for (int mt = 0; mt < 2; ++mt)
            #pragma unroll
            for (int nt = 0; nt < 4; ++nt)
                acc[mt][nt] = __builtin_amdgcn_mfma_f32_16x16x32_f16(af[mt], bf[nt], acc[mt][nt], 0, 0, 0);
        if (ks + 1 < nsteps) {
            *(float4*)&sA[cur ^ 1][aofs]  = pa0;
            *(float4*)&sB[cur ^ 1][bofs0] = pb0;
            *(float4*)&sB[cur ^ 1][bofs1] = pb1;
            if (ks + 2 < nsteps) {
                int ko = (ks + 2) << 5;
                pa0 = *(const float4*)(gA0 + ko);
                pb0 = *(const float4*)(gB0 + ko); pb1 = *(const float4*)(gB1 + ko);
            }
        }
        __syncthreads();
    }

    const int crow0 = m0 + wm * 32 + quad * 4;
    const int ccol0 = n0 + wn * 64 + l15;
    #pragma unroll
    for (int mt = 0; mt < 2; ++mt) {
        #pragma unroll
        for (int nt = 0; nt < 4; ++nt) {
            int col = ccol0 + nt * 16;    // interleaved output column
            float b = bias[col];
            #pragma unroll
            for (int rg = 0; rg < 4; ++rg) {
                int row = crow0 + mt * 16 + rg;
                float val = acc[mt][nt][rg] + b;
                if (out_mode == 1) {
                    C[(size_t)row * 1024 + col] = val;        // coalesced
                } else if (!(col & 1)) {
                    C[(size_t)row * 512 + (col >> 1)] = val;  // real part only
                }
            }
        }
    }
}

// ---------------------------------------------------------------------------
// chunkstate: MFMA, reads fp16 planes, writes Sc packed half2 (uint).
// ---------------------------------------------------------------------------
__global__ __launch_bounds__(256) void chunkstate_kernel(
    const _Float16* __restrict__ PL,
    const float* __restrict__ lgs, const float* __restrict__ lgz,
    const float* __restrict__ phs,
    unsigned int* __restrict__ ScU, float* __restrict__ Zc)
{
    __shared__ _Float16 wvTr[64 * 40], wvTi[64 * 40];      // [vd][u]
    __shared__ _Float16 kkTr[64 * 40], kkTi[64 * 40];      // [k][u]
    __shared__ float    Lgkz[32 * 65];                     // [u][k]

    const int tid = threadIdx.x;
    const int c = blockIdx.x & 63, h = blockIdx.x >> 6;

    float xs = lgs[h];
    float sps = fmaxf(xs, 0.f) + log1pf(expf(-fabsf(xs)));
    float ph = phs[h];
    float xz = lgz[h];
    float spz = fmaxf(xz, 0.f) + log1pf(expf(-fabsf(xz)));

    const _Float16* kkrP = PL + 3145728;
    const _Float16* kkiP = PL + 4194304;
    const _Float16* gkpP = PL + 5242880;
    const _Float16* vrP  = PL + 6291456;
    const _Float16* viP  = PL + 7340032;

    {
        const int u = tid >> 3, ks = (tid & 7) << 3;
        const size_t rofs = (size_t)(c * CL + u) * 512 + h * HDD + ks;
        half8 kr8 = *(const half8*)&kkrP[rofs];
        half8 ki8 = *(const half8*)&kkiP[rofs];
        half8 gk8 = *(const half8*)&gkpP[rofs];
        half8 vr8 = *(const half8*)&vrP[rofs];
        half8 vi8 = *(const half8*)&viP[rofs];
        float e = (float)(CL - 1 - u);
        float r = expf(-sps * e);
        float wAr = r * cosf(ph * e), wAi = r * sinf(ph * e);
        float wz = expf(-spz * e);
        #pragma unroll
        for (int j = 0; j < 8; ++j) {
            int kcol = ks + j;
            kkTr[kcol * 40 + u] = kr8[j];
            kkTi[kcol * 40 + u] = ki8[j];
            float vre = (float)vr8[j], vim = (float)vi8[j];
            wvTr[kcol * 40 + u] = (_Float16)(wAr * vre - wAi * vim);
            wvTi[kcol * 40 + u] = (_Float16)(wAr * vim + wAi * vre);
            Lgkz[u * 65 + kcol] = wz * (float)gk8[j];
        }
    }
    __syncthreads();

    const int w = tid >> 6, lane = tid & 63;
    const int quad = lane >> 4, l15 = lane & 15;
    const int arow = (w * 16 + l15) * 40 + quad * 8;
    half8 fvr = *(const half8*)&wvTr[arow];
    half8 fvi = *(const half8*)&wvTi[arow];
    unsigned int* out = ScU + ((size_t)(c * NH + h) << 12);
    #pragma unroll
    for (int kq = 0; kq < 4; ++kq) {
        int brow = (kq * 16 + l15) * 40 + quad * 8;
        half8 fkr  = *(const half8*)&kkTr[brow];
        half8 fki  = *(const half8*)&kkTi[brow];
        half8 fkiN = neg8r(fki);
        f32x4 Cr = {0.f, 0.f, 0.f, 0.f}, Ci = {0.f, 0.f, 0.f, 0.f};
        Cr = __builtin_amdgcn_mfma_f32_16x16x32_f16(fvr, fkr,  Cr, 0, 0, 0);
        Cr = __builtin_amdgcn_mfma_f32_16x16x32_f16(fvi, fkiN, Cr, 0, 0, 0);
        Ci = __builtin_amdgcn_mfma_f32_16x16x32_f16(fvr, fki,  Ci, 0, 0, 0);
        Ci = __builtin_amdgcn_mfma_f32_16x16x32_f16(fvi, fkr,  Ci, 0, 0, 0);
        #pragma unroll
        for (int reg = 0; reg < 4; ++reg) {
            int vd = w * 16 + quad * 4 + reg;
            out[vd * 64 + kq * 16 + l15] = pack2h(Cr[reg], Ci[reg]);
        }
    }
    if (tid < 64) {
        float z = 0.f;
        #pragma unroll
        for (int uu = 0; uu < 32; ++uu) z += Lgkz[uu * 65 + tid];
        Zc[(c * NH + h) * 64 + tid] = z;
    }
}

// ---------------------------------------------------------------------------
// chunkscan: exclusive prefix over chunks, packed half2 state,
// software-pipelined batch-8 loads.
// ---------------------------------------------------------------------------
__global__ __launch_bounds__(256) void chunkscan_kernel(
    const float* __restrict__ lgs, const float* __restrict__ lgz,
    const float* __restrict__ phs,
    unsigned int* __restrict__ ScU, float* __restrict__ Zc)
{
    const int bid = blockIdx.x, tid = threadIdx.x;
    if (bid < 128) {
        const int idx = bid * 256 + tid;
        const int h = idx >> 12, e = idx & 4095;
        float xs = lgs[h];
        float sps = fmaxf(xs, 0.f) + log1pf(expf(-fabsf(xs)));
        float ph = phs[h];
        float r = expf(-sps * (float)CL);
        float aLr = r * cosf(ph * (float)CL), aLi = r * sinf(ph * (float)CL);
        unsigned int* p = ScU + (size_t)h * 4096 + e;
        float pr = 0.f, pi = 0.f;
        unsigned int vcur[8], vnext[8];
        #pragma unroll
        for (int j = 0; j < 8; ++j) vcur[j] = p[(size_t)j * 32768];
        #pragma unroll
        for (int cb = 0; cb < 8; ++cb) {
            if (cb + 1 < 8) {
                #pragma unroll
                for (int j = 0; j < 8; ++j)
                    vnext[j] = p[(size_t)(((cb + 1) << 3) + j) * 32768];
            }
            #pragma unroll
            for (int j = 0; j < 8; ++j) {
                float2 tmp = unpack2h(vcur[j]);
                p[(size_t)((cb << 3) + j) * 32768] = pack2h(pr, pi);
                float nr = aLr * pr - aLi * pi + tmp.x;
                float ni = aLr * pi + aLi * pr + tmp.y;
                pr = nr; pi = ni;
            }
            #pragma unroll
            for (int j = 0; j < 8; ++j) vcur[j] = vnext[j];
        }
    } else {
        const int idx = (bid - 128) * 256 + tid;
        const int h = idx >> 6, k = idx & 63;
        float xz = lgz[h];
        float spz = fmaxf(xz, 0.f) + log1pf(expf(-fabsf(xz)));
        float azL = expf(-spz * (float)CL);
        float* p = Zc + h * 64 + k;
        float prev = 0.f;
        float vcur[8], vnext[8];
        #pragma unroll
        for (int j = 0; j < 8; ++j) vcur[j] = p[(size_t)j * 512];
        #pragma unroll
        for (int cb = 0; cb < 8; ++cb) {
            if (cb + 1 < 8) {
                #pragma unroll
                for (int j = 0; j < 8; ++j)
                    vnext[j] = p[(size_t)(((cb + 1) << 3) + j) * 512];
            }
            #pragma unroll
            for (int j = 0; j < 8; ++j) {
                float tmp = vcur[j];
                p[(size_t)((cb << 3) + j) * 512] = prev;
                prev = azL * prev + tmp;
            }
            #pragma unroll
            for (int j = 0; j < 8; ++j) vcur[j] = vnext[j];
        }
    }
}

// ---------------------------------------------------------------------------
// chunkout v4: Sp fragments loaded directly from global into registers;
// fp16 negations in registers; LDS ~44KB.
// ---------------------------------------------------------------------------
__global__ __launch_bounds__(256) void chunkout_kernel(
    const _Float16* __restrict__ PL,
    const unsigned int* __restrict__ SpU, const float* __restrict__ Zp,
    const float* __restrict__ lgs, const float* __restrict__ lgz,
    const float* __restrict__ phs,
    _Float16* __restrict__ Y2h)
{
    __shared__ _Float16 Lqr[32 * 72], Lqi[32 * 72];   // [t][k]
    __shared__ _Float16 Lkr[32 * 72], Lki[32 * 72];   // [u][k]
    __shared__ _Float16 Lgq[32 * 72], Lgk[32 * 72];
    __shared__ _Float16 Vtr[64 * 40], Vti[64 * 40];   // [vd][u]
    __shared__ _Float16 Wr_[32 * 40], Wi_[32 * 40];   // [t][u]
    __shared__ float  sDenP[2][32], sZdot[32], sDinv[32], sZp[64];
    __shared__ float2 s_apow[CL + 1];
    __shared__ float  s_azpow[CL + 1];

    const int tid = threadIdx.x;
    const int c = blockIdx.x & 63, h = blockIdx.x >> 6;
    const int w = tid >> 6, lane = tid & 63;
    const int quad = lane >> 4, l15 = lane & 15;

    // ---- Sp fragment prefetch (global -> regs), overlaps staging ----
    uint4 spv[4];
    {
        const unsigned int* bp = SpU + ((size_t)(c * NH + h) << 12) + (w * 16 + l15) * 64;
        #pragma unroll
        for (int s = 0; s < 2; ++s) {
            spv[s * 2]     = *(const uint4*)(bp + s * 32 + quad * 8);
            spv[s * 2 + 1] = *(const uint4*)(bp + s * 32 + quad * 8 + 4);
        }
    }

    if (tid <= CL) {
        float xs = lgs[h];
        float sps = fmaxf(xs, 0.f) + log1pf(expf(-fabsf(xs)));
        float ph = phs[h];
        float r = expf(-sps * (float)tid);
        s_apow[tid] = make_float2(r * cosf(ph * (float)tid), r * sinf(ph * (float)tid));
        float xz = lgz[h];
        float spz = fmaxf(xz, 0.f) + log1pf(expf(-fabsf(xz)));
        s_azpow[tid] = expf(-spz * (float)tid);
    }
    if (tid < 64) sZp[tid] = Zp[(c * NH + h) * 64 + tid];

    const _Float16* qfrP = PL;
    const _Float16* qfiP = PL + 1048576;
    const _Float16* gqpP = PL + 2097152;
    const _Float16* kkrP = PL + 3145728;
    const _Float16* kkiP = PL + 4194304;
    const _Float16* gkpP = PL + 5242880;
    const _Float16* vrP  = PL + 6291456;
    const _Float16* viP  = PL + 7340032;

    {
        const int u = tid >> 3, ks = (tid & 7) << 3;
        const size_t rofs = (size_t)(c * CL + u) * 512 + h * HDD + ks;
        half8 qr  = *(const half8*)&qfrP[rofs];
        half8 qi  = *(const half8*)&qfiP[rofs];
        half8 g8q = *(const half8*)&gqpP[rofs];
        half8 kr  = *(const half8*)&kkrP[rofs];
        half8 ki  = *(const half8*)&kkiP[rofs];
        half8 g8k = *(const half8*)&gkpP[rofs];
        half8 vr8 = *(const half8*)&vrP[rofs];
        half8 vi8 = *(const half8*)&viP[rofs];
        int ofs = u * 72 + ks;
        *(half8*)&Lqr[ofs] = qr;  *(half8*)&Lqi[ofs] = qi;
        *(half8*)&Lkr[ofs] = kr;  *(half8*)&Lki[ofs] = ki;
        *(half8*)&Lgq[ofs] = g8q; *(half8*)&Lgk[ofs] = g8k;
        #pragma unroll
        for (int j = 0; j < 8; ++j) {
            Vtr[(ks + j) * 40 + u] = vr8[j];
            Vti[(ks + j) * 40 + u] = vi8[j];
        }
    }
    __syncthreads();

    // ---- zdot[t] = Zp . gq[t] ----
    {
        const int t = tid >> 3, k8 = (tid & 7) << 3;
        float z = 0.f;
        #pragma unroll
        for (int j = 0; j < 8; ++j) z += sZp[k8 + j] * (float)Lgq[t * 72 + k8 + j];
        z += __shfl_xor(z, 1); z += __shfl_xor(z, 2); z += __shfl_xor(z, 4);
        if ((tid & 7) == 0) sZdot[t] = z;
    }

    // ---- unpack Sp fragments ----
    half8 fSr[2], fSi[2], fSiN[2];
    #pragma unroll
    for (int s = 0; s < 2; ++s) {
        unsigned int uu[8];
        *(uint4*)&uu[0] = spv[s * 2];
        *(uint4*)&uu[4] = spv[s * 2 + 1];
        #pragma unroll
        for (int j = 0; j < 8; ++j) {
            union { unsigned int u; _Float16 hh[2]; } z; z.u = uu[j];
            fSr[s][j] = z.hh[0]; fSi[s][j] = z.hh[1];
        }
        fSiN[s] = neg8r(fSi[s]);
    }

    const int th = w >> 1, uh = w & 1;
    const f32x4 zero = {0.f, 0.f, 0.f, 0.f};

    // ---- phase 1a: scores + den ----
    f32x4 Ar = zero, Ai = zero, Dn = zero;
    {
        const int qrow = (th * 16 + l15) * 72;
        const int krow = (uh * 16 + l15) * 72;
        #pragma unroll
        for (int s = 0; s < 2; ++s) {
            int ko = s * 32 + quad * 8;
            half8 fqr  = *(const half8*)&Lqr[qrow + ko];
            half8 fqi  = *(const half8*)&Lqi[qrow + ko];
            half8 fkr  = *(const half8*)&Lkr[krow + ko];
            half8 fki  = *(const half8*)&Lki[krow + ko];
            half8 fkiN = neg8r(fki);
            Ar = __builtin_amdgcn_mfma_f32_16x16x32_f16(fqr, fkr,  Ar, 0, 0, 0);
            Ar = __builtin_amdgcn_mfma_f32_16x16x32_f16(fqi, fkiN, Ar, 0, 0, 0);
            Ai = __builtin_amdgcn_mfma_f32_16x16x32_f16(fqr, fki,  Ai, 0, 0, 0);
            Ai = __builtin_amdgcn_mfma_f32_16x16x32_f16(fqi, fkr,  Ai, 0, 0, 0);
            half8 fgq = *(const half8*)&Lgq[qrow + ko];
            half8 fgk = *(const half8*)&Lgk[krow + ko];
            Dn = __builtin_amdgcn_mfma_f32_16x16x32_f16(fgq, fgk, Dn, 0, 0, 0);
        }
    }
    // ---- phase 1b: inter = Sp @ qf ----
    f32x4 IRr[2] = {zero, zero}, IRi[2] = {zero, zero};
    #pragma unroll
    for (int s = 0; s < 2; ++s) {
        int ko = s * 32 + quad * 8;
        #pragma unroll
        for (int t2 = 0; t2 < 2; ++t2) {
            int qrow = (t2 * 16 + l15) * 72 + ko;
            half8 fqr = *(const half8*)&Lqr[qrow];
            half8 fqi = *(const half8*)&Lqi[qrow];
            IRr[t2] = __builtin_amdgcn_mfma_f32_16x16x32_f16(fSr[s],  fqr, IRr[t2], 0, 0, 0);
            IRr[t2] = __builtin_amdgcn_mfma_f32_16x16x32_f16(fSiN[s], fqi, IRr[t2], 0, 0, 0);
            IRi[t2] = __builtin_amdgcn_mfma_f32_16x16x32_f16(fSr[s],  fqi, IRi[t2], 0, 0, 0);
            IRi[t2] = __builtin_amdgcn_mfma_f32_16x16x32_f16(fSi[s],  fqr, IRi[t2], 0, 0, 0);
        }
    }
    // ---- mask + decay -> Wr_/Wi_; den partials ----
    #pragma unroll
    for (int reg = 0; reg < 4; ++reg) {
        int t = th * 16 + quad * 4 + reg;
        int u = uh * 16 + l15;
        float wr = 0.f, wi = 0.f, dd = 0.f;
        if (u <= t) {
            float2 p = s_apow[t - u];
            wr = p.x * Ar[reg] - p.y * Ai[reg];
            wi = p.x * Ai[reg] + p.y * Ar[reg];
            dd = s_azpow[t - u] * Dn[reg];
        }
        Wr_[t * 40 + u] = (_Float16)wr;
        Wi_[t * 40 + u] = (_Float16)wi;
        dd += __shfl_xor(dd, 1); dd += __shfl_xor(dd, 2);
        dd += __shfl_xor(dd, 4); dd += __shfl_xor(dd, 8);
        if (l15 == 0) sDenP[uh][t] = dd;
    }
    __syncthreads();

    if (tid < 32) {
        float den = sDenP[0][tid] + sDenP[1][tid] + s_azpow[tid + 1] * sZdot[tid];
        sDinv[tid] = 1.f / (den + EPS_F);
    }

    // ---- phase 2: intra = vT @ sW^T ----
    f32x4 NRr[2] = {zero, zero}, NRi[2] = {zero, zero};
    {
        const int vrow = (w * 16 + l15) * 40 + quad * 8;
        half8 fvr = *(const half8*)&Vtr[vrow];
        half8 fvi = *(const half8*)&Vti[vrow];
        half8 fviN = neg8r(fvi);
        #pragma unroll
        for (int t2 = 0; t2 < 2; ++t2) {
            int trow = (t2 * 16 + l15) * 40 + quad * 8;
            half8 fWr = *(const half8*)&Wr_[trow];
            half8 fWi = *(const half8*)&Wi_[trow];
            NRr[t2] = __builtin_amdgcn_mfma_f32_16x16x32_f16(fvr,  fWr, NRr[t2], 0, 0, 0);
            NRr[t2] = __builtin_amdgcn_mfma_f32_16x16x32_f16(fviN, fWi, NRr[t2], 0, 0, 0);
            NRi[t2] = __builtin_amdgcn_mfma_f32_16x16x32_f16(fvr,  fWi, NRi[t2], 0, 0, 0);
            NRi[t2] = __builtin_amdgcn_mfma_f32_16x16x32_f16(fvi,  fWr, NRi[t2], 0, 0, 0);
        }
    }
    __syncthreads();

    // ---- epilogue ----
    #pragma unroll
    for (int t2 = 0; t2 < 2; ++t2) {
        int t = t2 * 16 + l15;
        float2 fac = s_apow[t + 1];
        float dinv = sDinv[t];
        half4 hre, him;
        #pragma unroll
        for (int reg = 0; reg < 4; ++reg) {
            float rx = NRr[t2][reg] + fac.x * IRr[t2][reg] - fac.y * IRi[t2][reg];
            float ry = NRi[t2][reg] + fac.x * IRi[t2][reg] + fac.y * IRr[t2][reg];
            hre[reg] = (_Float16)(rx * dinv);
            him[reg] = (_Float16)(ry * dinv);
        }
        int vd0 = w * 16 + quad * 4;
        _Float16* orow = Y2h + (size_t)(c * CL + t) * 1024 + h * HDD;
        *(half4*)&orow[vd0]       = hre;
        *(half4*)&orow[512 + vd0] = him;
    }
}

// ---------------------------------------------------------------------------
extern "C" void kernel_launch(void* const* d_in, const int* in_sizes, int n_in,
                              void* d_out, int out_size, void* d_ws, size_t ws_size,
                              hipStream_t stream)
{
    const float* x    = (const float*)d_in[0];
    const float* q_wr = (const float*)d_in[1];
    const float* q_wi = (const float*)d_in[2];
    const float* q_br = (const float*)d_in[3];
    const float* q_bi = (const float*)d_in[4];
    const float* k_wr = (const float*)d_in[5];
    const float* k_wi = (const float*)d_in[6];
    const float* k_br = (const float*)d_in[7];
    const float* k_bi = (const float*)d_in[8];
    const float* v_wr = (const float*)d_in[9];
    const float* v_wi = (const float*)d_in[10];
    const float* v_br = (const float*)d_in[11];
    const float* v_bi = (const float*)d_in[12];
    const float* o_wr = (const float*)d_in[13];
    const float* o_wi = (const float*)d_in[14];
    const float* o_br = (const float*)d_in[15];
    const float* o_bi = (const float*)d_in[16];
    const float* log_decay_s = (const float*)d_in[17];
    const float* log_decay_z = (const float*)d_in[18];
    const float* phase       = (const float*)d_in[19];

    float* ws = (float*)d_ws;
    float* Zcf  = ws;                          // 32768 f
    float* ball = ws + 32768;                  // 3072 f
    float* b2a  = ws + 35840;                  // 1024 f
    _Float16* WTa = (_Float16*)(ws + 36864);   // 1572864 h
    _Float16* W2T = WTa + 1572864;             // 1048576 h
    _Float16* Y2h = W2T + 1048576;             // 2097152 h
    _Float16* PL  = Y2h + 2097152;             // 8 x 1048576 h
    unsigned int* ScU = (unsigned int*)(PL + 8388608);  // 2097152 u32

    int out_mode = (out_size == 2048 * 1024) ? 1 : 0;

    prep_kernel<<<656, 256, 0, stream>>>(q_wr, q_wi, k_wr, k_wi, v_wr, v_wi,
                                         o_wr, o_wi, q_br, q_bi, k_br, k_bi,
                                         v_br, v_bi, o_br, o_bi,
                                         WTa, W2T, ball, b2a);

    gemm_qkv_kernel<<<dim3(24, 32), 256, 0, stream>>>(x, WTa, ball, PL);

    chunkstate_kernel<<<512, 256, 0, stream>>>(PL, log_decay_s, log_decay_z, phase,
                                               ScU, Zcf);

    chunkscan_kernel<<<130, 256, 0, stream>>>(log_decay_s, log_decay_z, phase, ScU, Zcf);

    chunkout_kernel<<<512, 256, 0, stream>>>(PL, ScU, Zcf, log_decay_s, log_decay_z,
                                             phase, Y2h);

    gemm_f16_kernel<<<dim3(8, 32), 256, 0, stream>>>(Y2h, W2T, b2a, (float*)d_out,
                                                     1024, out_mode);
}

// Round 13
// 65.497 us; speedup vs baseline: 1.0728x; 1.0728x over previous
//
#include <hip/hip_runtime.h>
#include <math.h>

#define TT 2048
#define NH 8
#define HDD 64
#define CL 32          // chunk length
#define NC 64          // number of chunks
#define EPS_F 1e-8f

typedef __attribute__((ext_vector_type(8))) _Float16 half8;
typedef __attribute__((ext_vector_type(4))) _Float16 half4;
typedef __attribute__((ext_vector_type(4))) float    f32x4;

__device__ __forceinline__ unsigned int pack2h(float a, float b) {
    union { _Float16 h[2]; unsigned int u; } z;
    z.h[0] = (_Float16)a; z.h[1] = (_Float16)b; return z.u;
}
__device__ __forceinline__ float2 unpack2h(unsigned int w) {
    union { unsigned int u; _Float16 h[2]; } z; z.u = w;
    return make_float2((float)z.h[0], (float)z.h[1]);
}
// register-level negate: XOR fp16 sign bits
__device__ __forceinline__ half8 neg8r(half8 v) {
    union { half8 h; unsigned int u[4]; } z; z.h = v;
    #pragma unroll
    for (int i = 0; i < 4; ++i) z.u[i] ^= 0x80008000u;
    return z.h;
}
__device__ __forceinline__ half8 cvt8f(float4 a, float4 b) {
    half8 r;
    r[0]=(_Float16)a.x; r[1]=(_Float16)a.y; r[2]=(_Float16)a.z; r[3]=(_Float16)a.w;
    r[4]=(_Float16)b.x; r[5]=(_Float16)b.y; r[6]=(_Float16)b.z; r[7]=(_Float16)b.w;
    return r;
}

// ---------------------------------------------------------------------------
// prep: fused wconv (blocks 0..383) + w2prep (384..639) + biasprep (640..655)
// W2T rows permuted to OUTPUT-INTERLEAVED order: o = n<512 ? 2n : 2(n-512)+1,
// so GEMM2's epilogue writes are contiguous fp32 (no stride-2 scatter).
// ---------------------------------------------------------------------------
__global__ __launch_bounds__(256) void prep_kernel(
    const float* __restrict__ q_wr, const float* __restrict__ q_wi,
    const float* __restrict__ k_wr, const float* __restrict__ k_wi,
    const float* __restrict__ v_wr, const float* __restrict__ v_wi,
    const float* __restrict__ o_wr, const float* __restrict__ o_wi,
    const float* __restrict__ bq_r, const float* __restrict__ bq_i,
    const float* __restrict__ bk_r, const float* __restrict__ bk_i,
    const float* __restrict__ bv_r, const float* __restrict__ bv_i,
    const float* __restrict__ o_br, const float* __restrict__ o_bi,
    _Float16* __restrict__ WT, _Float16* __restrict__ W2T,
    float* __restrict__ ball, float* __restrict__ b2a)
{
    __shared__ float tile[64][65];
    const int bid = blockIdx.x, tid = threadIdx.x;
    if (bid < 384) {
        const int z = bid >> 6, t = bid & 63;       // z in 0..5
        const int k0 = (t >> 3) * 64, n0 = (t & 7) * 64;
        const int g = z >> 1, p = z & 1;
        const float* W;
        switch (z) {
          case 0: W = q_wr; break;
          case 1: W = q_wi; break;
          case 2: W = k_wr; break;
          case 3: W = k_wi; break;
          case 4: W = v_wr; break;
          default: W = v_wi; break;                 // z == 5
        }
        #pragma unroll
        for (int it = 0; it < 16; ++it) {
            int idx = it * 256 + tid;
            tile[idx >> 6][idx & 63] = W[(size_t)(k0 + (idx >> 6)) * 512 + n0 + (idx & 63)];
        }
        __syncthreads();
        #pragma unroll
        for (int it = 0; it < 16; ++it) {
            int idx = it * 256 + tid;
            int nr = idx >> 6, kc = idx & 63;
            int n = n0 + nr;
            int R = g * 1024 + ((n >> 4) << 5) + p * 16 + (n & 15);
            WT[(size_t)R * 512 + k0 + kc] = (_Float16)tile[kc][nr];
        }
    } else if (bid < 640) {
        const int t = bid - 384;
        const int i0 = (t >> 4) * 64, j0 = (t & 15) * 64;
        const float* src; float sgn; int io, jo;
        if (i0 < 512) {
            if (j0 < 512) { src = o_wr; sgn = 1.f;  io = i0; jo = j0; }
            else          { src = o_wi; sgn = 1.f;  io = i0; jo = j0 - 512; }
        } else {
            if (j0 < 512) { src = o_wi; sgn = -1.f; io = i0 - 512; jo = j0; }
            else          { src = o_wr; sgn = 1.f;  io = i0 - 512; jo = j0 - 512; }
        }
        #pragma unroll
        for (int it = 0; it < 16; ++it) {
            int idx = it * 256 + tid;
            tile[idx >> 6][idx & 63] = sgn * src[(size_t)(io + (idx >> 6)) * 512 + jo + (idx & 63)];
        }
        __syncthreads();
        #pragma unroll
        for (int it = 0; it < 16; ++it) {
            int idx = it * 256 + tid;
            int nr = idx >> 6, kc = idx & 63;
            int n = j0 + nr;
            int o = (n < 512) ? (2 * n) : (2 * (n - 512) + 1);   // interleave
            W2T[(size_t)o * 1024 + i0 + kc] = (_Float16)tile[kc][nr];
        }
    } else {
        int idx = (bid - 640) * 256 + tid;   // 0..4095
        if (idx < 3072) {
            int g = idx >> 10, wq = idx & 1023;
            int p = (wq >> 4) & 1;
            int n = ((wq >> 5) << 4) | (wq & 15);
            float v;
            switch (g * 2 + p) {
              case 0: v = bq_r[n]; break;
              case 1: v = bq_i[n]; break;
              case 2: v = bk_r[n]; break;
              case 3: v = bk_i[n]; break;
              case 4: v = bv_r[n]; break;
              default: v = bv_i[n]; break;
            }
            ball[idx] = v;
        } else {
            int j = idx - 3072;
            float v = (j < 512) ? o_br[j] : o_bi[j - 512];
            int o = (j < 512) ? (2 * j) : (2 * (j - 512) + 1);   // interleave
            b2a[o] = v;
        }
    }
}

// ---------------------------------------------------------------------------
// GEMM1 fused w/ feature epilogue. BM=64, double-buffered LDS, 1 barrier/step.
// Epilogue: direct per-thread plane writes (r11-proven).
// grid (24 n-tiles, 32 m-tiles)
// ---------------------------------------------------------------------------
__global__ __launch_bounds__(256) void gemm_qkv_kernel(
    const float* __restrict__ X,
    const _Float16* __restrict__ BT,
    const float* __restrict__ ball,
    _Float16* __restrict__ PL)
{
    __shared__ _Float16 sA[2][64 * 32];
    __shared__ _Float16 sB[2][128 * 32];
    const int tid = threadIdx.x;
    const int bx = blockIdx.x, by = blockIdx.y;
    const int m0 = by * 64, R0 = bx * 128;
    const int g = bx >> 3;
    const int nb = (bx & 7) * 64;
    const int lane = tid & 63;
    const int w = tid >> 6, wm = w >> 1, wn = w & 1;
    const int quad = lane >> 4, l15 = lane & 15;

    f32x4 acc[2][4];
    #pragma unroll
    for (int i = 0; i < 2; ++i)
        #pragma unroll
        for (int j = 0; j < 4; ++j) { f32x4 z = {0.f, 0.f, 0.f, 0.f}; acc[i][j] = z; }

    const int rA0 = tid >> 2, sq = tid & 3;
    const float* gA0 = X + (size_t)(m0 + rA0) * 512 + (sq ^ ((rA0 >> 1) & 3)) * 8;
    const int aofs = rA0 * 32 + sq * 8;

    const int rB0 = tid >> 2, rB1 = rB0 + 64;
    const _Float16* gB0 = BT + (size_t)(R0 + rB0) * 512 + (sq ^ ((rB0 >> 1) & 3)) * 8;
    const _Float16* gB1 = BT + (size_t)(R0 + rB1) * 512 + (sq ^ ((rB1 >> 1) & 3)) * 8;
    const int bofs0 = rB0 * 32 + sq * 8;
    const int bofs1 = rB1 * 32 + sq * 8;

    const int arow = wm * 32 + l15;
    const int brow = wn * 64 + l15;

    float4 a00 = *(const float4*)gA0, a01 = *(const float4*)(gA0 + 4);
    float4 pb0 = *(const float4*)gB0, pb1 = *(const float4*)gB1;
    *(half8*)&sA[0][aofs]  = cvt8f(a00, a01);
    *(float4*)&sB[0][bofs0] = pb0;
    *(float4*)&sB[0][bofs1] = pb1;
    a00 = *(const float4*)(gA0 + 32); a01 = *(const float4*)(gA0 + 36);
    pb0 = *(const float4*)(gB0 + 32); pb1 = *(const float4*)(gB1 + 32);
    __syncthreads();

    for (int ks = 0; ks < 16; ++ks) {
        const int cur = ks & 1;
        half8 af[2], bf[4];
        #pragma unroll
        for (int mt = 0; mt < 2; ++mt) {
            int r = arow + mt * 16;
            int qp = quad ^ ((r >> 1) & 3);
            af[mt] = *(half8*)&sA[cur][r * 32 + qp * 8];
        }
        #pragma unroll
        for (int nt = 0; nt < 4; ++nt) {
            int r = brow + nt * 16;
            int qp = quad ^ ((r >> 1) & 3);
            bf[nt] = *(half8*)&sB[cur][r * 32 + qp * 8];
        }
        #pragma unroll
        for (int mt = 0; mt < 2; ++mt)
            #pragma unroll
            for (int nt = 0; nt < 4; ++nt)
                acc[mt][nt] = __builtin_amdgcn_mfma_f32_16x16x32_f16(af[mt], bf[nt], acc[mt][nt], 0, 0, 0);
        if (ks + 1 < 16) {
            *(half8*)&sA[cur ^ 1][aofs]  = cvt8f(a00, a01);
            *(float4*)&sB[cur ^ 1][bofs0] = pb0;
            *(float4*)&sB[cur ^ 1][bofs1] = pb1;
            if (ks + 2 < 16) {
                int ko = (ks + 2) << 5;
                a00 = *(const float4*)(gA0 + ko); a01 = *(const float4*)(gA0 + ko + 4);
                pb0 = *(const float4*)(gB0 + ko); pb1 = *(const float4*)(gB1 + ko);
            }
        }
        __syncthreads();
    }

    _Float16* qfr = PL;
    _Float16* qfi = PL + 1048576;
    _Float16* gqp = PL + 2097152;
    _Float16* kkr = PL + 3145728;
    _Float16* kki = PL + 4194304;
    _Float16* gkp = PL + 5242880;
    _Float16* vrp = PL + 6291456;
    _Float16* vip = PL + 7340032;

    const int crow0 = m0 + wm * 32 + quad * 4;
    #pragma unroll
    for (int j = 0; j < 2; ++j) {
        int col = nb + wn * 32 + j * 16 + l15;
        float bre = ball[R0 + wn * 64 + j * 32 + l15];
        float bim = ball[R0 + wn * 64 + j * 32 + 16 + l15];
        #pragma unroll
        for (int mt = 0; mt < 2; ++mt) {
            #pragma unroll
            for (int reg = 0; reg < 4; ++reg) {
                int row = crow0 + mt * 16 + reg;
                size_t ofs = (size_t)row * 512 + col;
                float xr = acc[mt][2 * j][reg] + bre;
                float xi = acc[mt][2 * j + 1][reg] + bim;
                if (g == 0) {
                    float gv = sqrtf(xr * xr + xi * xi);
                    float f = gv / (gv + EPS_F);
                    qfr[ofs] = (_Float16)(xr * f);
                    qfi[ofs] = (_Float16)(xi * f);
                    gqp[ofs] = (_Float16)gv;
                } else if (g == 1) {
                    float gv = sqrtf(xr * xr + xi * xi);
                    float f = gv / (gv + EPS_F);
                    kkr[ofs] = (_Float16)(xr * f);
                    kki[ofs] = (_Float16)(-xi * f);   // conj
                    gkp[ofs] = (_Float16)gv;
                } else {
                    vrp[ofs] = (_Float16)xr;
                    vip[ofs] = (_Float16)xi;
                }
            }
        }
    }
}

// ---------------------------------------------------------------------------
// GEMM2: out = Y2h @ W2T'^T + b2a (interleaved cols -> coalesced writes).
// BM=64, double-buffered, 1 barrier/step. grid (8, 32).
// ---------------------------------------------------------------------------
__global__ __launch_bounds__(256) void gemm_f16_kernel(
    const _Float16* __restrict__ A,
    const _Float16* __restrict__ BT,
    const float* __restrict__ bias,
    float* __restrict__ C,
    int K, int out_mode)
{
    __shared__ _Float16 sA[2][64 * 32];
    __shared__ _Float16 sB[2][128 * 32];
    const int tid = threadIdx.x;
    const int m0 = blockIdx.y * 64, n0 = blockIdx.x * 128;
    const int lane = tid & 63;
    const int w = tid >> 6, wm = w >> 1, wn = w & 1;
    const int quad = lane >> 4, l15 = lane & 15;

    f32x4 acc[2][4];
    #pragma unroll
    for (int i = 0; i < 2; ++i)
        #pragma unroll
        for (int j = 0; j < 4; ++j) { f32x4 z = {0.f, 0.f, 0.f, 0.f}; acc[i][j] = z; }

    const int rA0 = tid >> 2, sq = tid & 3;
    const _Float16* gA0 = A + (size_t)(m0 + rA0) * K + (sq ^ ((rA0 >> 1) & 3)) * 8;
    const int aofs = rA0 * 32 + sq * 8;

    const int rB0 = tid >> 2, rB1 = rB0 + 64;
    const _Float16* gB0 = BT + (size_t)(n0 + rB0) * K + (sq ^ ((rB0 >> 1) & 3)) * 8;
    const _Float16* gB1 = BT + (size_t)(n0 + rB1) * K + (sq ^ ((rB1 >> 1) & 3)) * 8;
    const int bofs0 = rB0 * 32 + sq * 8;
    const int bofs1 = rB1 * 32 + sq * 8;

    const int arow = wm * 32 + l15;
    const int brow = wn * 64 + l15;
    const int nsteps = K >> 5;

    float4 pa0 = *(const float4*)gA0;
    float4 pb0 = *(const float4*)gB0, pb1 = *(const float4*)gB1;
    *(float4*)&sA[0][aofs]  = pa0;
    *(float4*)&sB[0][bofs0] = pb0;
    *(float4*)&sB[0][bofs1] = pb1;
    if (nsteps > 1) {
        pa0 = *(const float4*)(gA0 + 32);
        pb0 = *(const float4*)(gB0 + 32); pb1 = *(const float4*)(gB1 + 32);
    }
    __syncthreads();

    for (int ks = 0; ks < nsteps; ++ks) {
        const int cur = ks & 1;
        half8 af[2], bf[4];
        #pragma unroll
        for (int mt = 0; mt < 2; ++mt) {
            int r = arow + mt * 16;
            int qp = quad ^ ((r >> 1) & 3);
            af[mt] = *(half8*)&sA[cur][r * 32 + qp * 8];
        }
        #pragma unroll
        for (int nt = 0; nt < 4; ++nt) {
            int r = brow + nt * 16;
            int qp = quad ^ ((r >> 1) & 3);
            bf[nt] = *(half8*)&sB[cur][r * 32 + qp * 8];
        }
        #pragma unroll
        for (int mt = 0; mt < 2; ++mt)
            #pragma unroll
            for (int nt = 0; nt < 4; ++nt)
                acc[mt][nt] = __builtin_amdgcn_mfma_f32_16x16x32_f16(af[mt], bf[nt], acc[mt][nt], 0, 0, 0);
        if (ks + 1 < nsteps) {
            *(float4*)&sA[cur ^ 1][aofs]  = pa0;
            *(float4*)&sB[cur ^ 1][bofs0] = pb0;
            *(float4*)&sB[cur ^ 1][bofs1] = pb1;
            if (ks + 2 < nsteps) {
                int ko = (ks + 2) << 5;
                pa0 = *(const float4*)(gA0 + ko);
                pb0 = *(const float4*)(gB0 + ko); pb1 = *(const float4*)(gB1 + ko);
            }
        }
        __syncthreads();
    }

    const int crow0 = m0 + wm * 32 + quad * 4;
    const int ccol0 = n0 + wn * 64 + l15;
    #pragma unroll
    for (int mt = 0; mt < 2; ++mt) {
        #pragma unroll
        for (int nt = 0; nt < 4; ++nt) {
            int col = ccol0 + nt * 16;    // interleaved output column
            float b = bias[col];
            #pragma unroll
            for (int rg = 0; rg < 4; ++rg) {
                int row = crow0 + mt * 16 + rg;
                float val = acc[mt][nt][rg] + b;
                if (out_mode == 1) {
                    C[(size_t)row * 1024 + col] = val;        // coalesced
                } else if (!(col & 1)) {
                    C[(size_t)row * 512 + (col >> 1)] = val;  // real part only
                }
            }
        }
    }
}

// ---------------------------------------------------------------------------
// chunkstate: MFMA, reads fp16 planes, writes Sc packed half2 (uint).
// ---------------------------------------------------------------------------
__global__ __launch_bounds__(256) void chunkstate_kernel(
    const _Float16* __restrict__ PL,
    const float* __restrict__ lgs, const float* __restrict__ lgz,
    const float* __restrict__ phs,
    unsigned int* __restrict__ ScU, float* __restrict__ Zc)
{
    __shared__ _Float16 wvTr[64 * 40], wvTi[64 * 40];      // [vd][u]
    __shared__ _Float16 kkTr[64 * 40], kkTi[64 * 40];      // [k][u]
    __shared__ float    Lgkz[32 * 65];                     // [u][k]

    const int tid = threadIdx.x;
    const int c = blockIdx.x & 63, h = blockIdx.x >> 6;

    float xs = lgs[h];
    float sps = fmaxf(xs, 0.f) + log1pf(expf(-fabsf(xs)));
    float ph = phs[h];
    float xz = lgz[h];
    float spz = fmaxf(xz, 0.f) + log1pf(expf(-fabsf(xz)));

    const _Float16* kkrP = PL + 3145728;
    const _Float16* kkiP = PL + 4194304;
    const _Float16* gkpP = PL + 5242880;
    const _Float16* vrP  = PL + 6291456;
    const _Float16* viP  = PL + 7340032;

    {
        const int u = tid >> 3, ks = (tid & 7) << 3;
        const size_t rofs = (size_t)(c * CL + u) * 512 + h * HDD + ks;
        half8 kr8 = *(const half8*)&kkrP[rofs];
        half8 ki8 = *(const half8*)&kkiP[rofs];
        half8 gk8 = *(const half8*)&gkpP[rofs];
        half8 vr8 = *(const half8*)&vrP[rofs];
        half8 vi8 = *(const half8*)&viP[rofs];
        float e = (float)(CL - 1 - u);
        float r = expf(-sps * e);
        float wAr = r * cosf(ph * e), wAi = r * sinf(ph * e);
        float wz = expf(-spz * e);
        #pragma unroll
        for (int j = 0; j < 8; ++j) {
            int kcol = ks + j;
            kkTr[kcol * 40 + u] = kr8[j];
            kkTi[kcol * 40 + u] = ki8[j];
            float vre = (float)vr8[j], vim = (float)vi8[j];
            wvTr[kcol * 40 + u] = (_Float16)(wAr * vre - wAi * vim);
            wvTi[kcol * 40 + u] = (_Float16)(wAr * vim + wAi * vre);
            Lgkz[u * 65 + kcol] = wz * (float)gk8[j];
        }
    }
    __syncthreads();

    const int w = tid >> 6, lane = tid & 63;
    const int quad = lane >> 4, l15 = lane & 15;
    const int arow = (w * 16 + l15) * 40 + quad * 8;
    half8 fvr = *(const half8*)&wvTr[arow];
    half8 fvi = *(const half8*)&wvTi[arow];
    unsigned int* out = ScU + ((size_t)(c * NH + h) << 12);
    #pragma unroll
    for (int kq = 0; kq < 4; ++kq) {
        int brow = (kq * 16 + l15) * 40 + quad * 8;
        half8 fkr  = *(const half8*)&kkTr[brow];
        half8 fki  = *(const half8*)&kkTi[brow];
        half8 fkiN = neg8r(fki);
        f32x4 Cr = {0.f, 0.f, 0.f, 0.f}, Ci = {0.f, 0.f, 0.f, 0.f};
        Cr = __builtin_amdgcn_mfma_f32_16x16x32_f16(fvr, fkr,  Cr, 0, 0, 0);
        Cr = __builtin_amdgcn_mfma_f32_16x16x32_f16(fvi, fkiN, Cr, 0, 0, 0);
        Ci = __builtin_amdgcn_mfma_f32_16x16x32_f16(fvr, fki,  Ci, 0, 0, 0);
        Ci = __builtin_amdgcn_mfma_f32_16x16x32_f16(fvi, fkr,  Ci, 0, 0, 0);
        #pragma unroll
        for (int reg = 0; reg < 4; ++reg) {
            int vd = w * 16 + quad * 4 + reg;
            out[vd * 64 + kq * 16 + l15] = pack2h(Cr[reg], Ci[reg]);
        }
    }
    if (tid < 64) {
        float z = 0.f;
        #pragma unroll
        for (int uu = 0; uu < 32; ++uu) z += Lgkz[uu * 65 + tid];
        Zc[(c * NH + h) * 64 + tid] = z;
    }
}

// ---------------------------------------------------------------------------
// chunkscan: exclusive prefix over chunks, packed half2 state,
// software-pipelined batch-8 loads.
// ---------------------------------------------------------------------------
__global__ __launch_bounds__(256) void chunkscan_kernel(
    const float* __restrict__ lgs, const float* __restrict__ lgz,
    const float* __restrict__ phs,
    unsigned int* __restrict__ ScU, float* __restrict__ Zc)
{
    const int bid = blockIdx.x, tid = threadIdx.x;
    if (bid < 128) {
        const int idx = bid * 256 + tid;
        const int h = idx >> 12, e = idx & 4095;
        float xs = lgs[h];
        float sps = fmaxf(xs, 0.f) + log1pf(expf(-fabsf(xs)));
        float ph = phs[h];
        float r = expf(-sps * (float)CL);
        float aLr = r * cosf(ph * (float)CL), aLi = r * sinf(ph * (float)CL);
        unsigned int* p = ScU + (size_t)h * 4096 + e;
        float pr = 0.f, pi = 0.f;
        unsigned int vcur[8], vnext[8];
        #pragma unroll
        for (int j = 0; j < 8; ++j) vcur[j] = p[(size_t)j * 32768];
        #pragma unroll
        for (int cb = 0; cb < 8; ++cb) {
            if (cb + 1 < 8) {
                #pragma unroll
                for (int j = 0; j < 8; ++j)
                    vnext[j] = p[(size_t)(((cb + 1) << 3) + j) * 32768];
            }
            #pragma unroll
            for (int j = 0; j < 8; ++j) {
                float2 tmp = unpack2h(vcur[j]);
                p[(size_t)((cb << 3) + j) * 32768] = pack2h(pr, pi);
                float nr = aLr * pr - aLi * pi + tmp.x;
                float ni = aLr * pi + aLi * pr + tmp.y;
                pr = nr; pi = ni;
            }
            #pragma unroll
            for (int j = 0; j < 8; ++j) vcur[j] = vnext[j];
        }
    } else {
        const int idx = (bid - 128) * 256 + tid;
        const int h = idx >> 6, k = idx & 63;
        float xz = lgz[h];
        float spz = fmaxf(xz, 0.f) + log1pf(expf(-fabsf(xz)));
        float azL = expf(-spz * (float)CL);
        float* p = Zc + h * 64 + k;
        float prev = 0.f;
        float vcur[8], vnext[8];
        #pragma unroll
        for (int j = 0; j < 8; ++j) vcur[j] = p[(size_t)j * 512];
        #pragma unroll
        for (int cb = 0; cb < 8; ++cb) {
            if (cb + 1 < 8) {
                #pragma unroll
                for (int j = 0; j < 8; ++j)
                    vnext[j] = p[(size_t)(((cb + 1) << 3) + j) * 512];
            }
            #pragma unroll
            for (int j = 0; j < 8; ++j) {
                float tmp = vcur[j];
                p[(size_t)((cb << 3) + j) * 512] = prev;
                prev = azL * prev + tmp;
            }
            #pragma unroll
            for (int j = 0; j < 8; ++j) vcur[j] = vnext[j];
        }
    }
}

// ---------------------------------------------------------------------------
// chunkout v4: Sp fragments loaded directly from global into registers;
// fp16 negations in registers; LDS ~44KB.
// ---------------------------------------------------------------------------
__global__ __launch_bounds__(256) void chunkout_kernel(
    const _Float16* __restrict__ PL,
    const unsigned int* __restrict__ SpU, const float* __restrict__ Zp,
    const float* __restrict__ lgs, const float* __restrict__ lgz,
    const float* __restrict__ phs,
    _Float16* __restrict__ Y2h)
{
    __shared__ _Float16 Lqr[32 * 72], Lqi[32 * 72];   // [t][k]
    __shared__ _Float16 Lkr[32 * 72], Lki[32 * 72];   // [u][k]
    __shared__ _Float16 Lgq[32 * 72], Lgk[32 * 72];
    __shared__ _Float16 Vtr[64 * 40], Vti[64 * 40];   // [vd][u]
    __shared__ _Float16 Wr_[32 * 40], Wi_[32 * 40];   // [t][u]
    __shared__ float  sDenP[2][32], sZdot[32], sDinv[32], sZp[64];
    __shared__ float2 s_apow[CL + 1];
    __shared__ float  s_azpow[CL + 1];

    const int tid = threadIdx.x;
    const int c = blockIdx.x & 63, h = blockIdx.x >> 6;
    const int w = tid >> 6, lane = tid & 63;
    const int quad = lane >> 4, l15 = lane & 15;

    // ---- Sp fragment prefetch (global -> regs), overlaps staging ----
    uint4 spv[4];
    {
        const unsigned int* bp = SpU + ((size_t)(c * NH + h) << 12) + (w * 16 + l15) * 64;
        #pragma unroll
        for (int s = 0; s < 2; ++s) {
            spv[s * 2]     = *(const uint4*)(bp + s * 32 + quad * 8);
            spv[s * 2 + 1] = *(const uint4*)(bp + s * 32 + quad * 8 + 4);
        }
    }

    if (tid <= CL) {
        float xs = lgs[h];
        float sps = fmaxf(xs, 0.f) + log1pf(expf(-fabsf(xs)));
        float ph = phs[h];
        float r = expf(-sps * (float)tid);
        s_apow[tid] = make_float2(r * cosf(ph * (float)tid), r * sinf(ph * (float)tid));
        float xz = lgz[h];
        float spz = fmaxf(xz, 0.f) + log1pf(expf(-fabsf(xz)));
        s_azpow[tid] = expf(-spz * (float)tid);
    }
    if (tid < 64) sZp[tid] = Zp[(c * NH + h) * 64 + tid];

    const _Float16* qfrP = PL;
    const _Float16* qfiP = PL + 1048576;
    const _Float16* gqpP = PL + 2097152;
    const _Float16* kkrP = PL + 3145728;
    const _Float16* kkiP = PL + 4194304;
    const _Float16* gkpP = PL + 5242880;
    const _Float16* vrP  = PL + 6291456;
    const _Float16* viP  = PL + 7340032;

    {
        const int u = tid >> 3, ks = (tid & 7) << 3;
        const size_t rofs = (size_t)(c * CL + u) * 512 + h * HDD + ks;
        half8 qr  = *(const half8*)&qfrP[rofs];
        half8 qi  = *(const half8*)&qfiP[rofs];
        half8 g8q = *(const half8*)&gqpP[rofs];
        half8 kr  = *(const half8*)&kkrP[rofs];
        half8 ki  = *(const half8*)&kkiP[rofs];
        half8 g8k = *(const half8*)&gkpP[rofs];
        half8 vr8 = *(const half8*)&vrP[rofs];
        half8 vi8 = *(const half8*)&viP[rofs];
        int ofs = u * 72 + ks;
        *(half8*)&Lqr[ofs] = qr;  *(half8*)&Lqi[ofs] = qi;
        *(half8*)&Lkr[ofs] = kr;  *(half8*)&Lki[ofs] = ki;
        *(half8*)&Lgq[ofs] = g8q; *(half8*)&Lgk[ofs] = g8k;
        #pragma unroll
        for (int j = 0; j < 8; ++j) {
            Vtr[(ks + j) * 40 + u] = vr8[j];
            Vti[(ks + j) * 40 + u] = vi8[j];
        }
    }
    __syncthreads();

    // ---- zdot[t] = Zp . gq[t] ----
    {
        const int t = tid >> 3, k8 = (tid & 7) << 3;
        float z = 0.f;
        #pragma unroll
        for (int j = 0; j < 8; ++j) z += sZp[k8 + j] * (float)Lgq[t * 72 + k8 + j];
        z += __shfl_xor(z, 1); z += __shfl_xor(z, 2); z += __shfl_xor(z, 4);
        if ((tid & 7) == 0) sZdot[t] = z;
    }

    // ---- unpack Sp fragments ----
    half8 fSr[2], fSi[2], fSiN[2];
    #pragma unroll
    for (int s = 0; s < 2; ++s) {
        unsigned int uu[8];
        *(uint4*)&uu[0] = spv[s * 2];
        *(uint4*)&uu[4] = spv[s * 2 + 1];
        #pragma unroll
        for (int j = 0; j < 8; ++j) {
            union { unsigned int u; _Float16 hh[2]; } z; z.u = uu[j];
            fSr[s][j] = z.hh[0]; fSi[s][j] = z.hh[1];
        }
        fSiN[s] = neg8r(fSi[s]);
    }

    const int th = w >> 1, uh = w & 1;
    const f32x4 zero = {0.f, 0.f, 0.f, 0.f};

    // ---- phase 1a: scores + den ----
    f32x4 Ar = zero, Ai = zero, Dn = zero;
    {
        const int qrow = (th * 16 + l15) * 72;
        const int krow = (uh * 16 + l15) * 72;
        #pragma unroll
        for (int s = 0; s < 2; ++s) {
            int ko = s * 32 + quad * 8;
            half8 fqr  = *(const half8*)&Lqr[qrow + ko];
            half8 fqi  = *(const half8*)&Lqi[qrow + ko];
            half8 fkr  = *(const half8*)&Lkr[krow + ko];
            half8 fki  = *(const half8*)&Lki[krow + ko];
            half8 fkiN = neg8r(fki);
            Ar = __builtin_amdgcn_mfma_f32_16x16x32_f16(fqr, fkr,  Ar, 0, 0, 0);
            Ar = __builtin_amdgcn_mfma_f32_16x16x32_f16(fqi, fkiN, Ar, 0, 0, 0);
            Ai = __builtin_amdgcn_mfma_f32_16x16x32_f16(fqr, fki,  Ai, 0, 0, 0);
            Ai = __builtin_amdgcn_mfma_f32_16x16x32_f16(fqi, fkr,  Ai, 0, 0, 0);
            half8 fgq = *(const half8*)&Lgq[qrow + ko];
            half8 fgk = *(const half8*)&Lgk[krow + ko];
            Dn = __builtin_amdgcn_mfma_f32_16x16x32_f16(fgq, fgk, Dn, 0, 0, 0);
        }
    }
    // ---- phase 1b: inter = Sp @ qf ----
    f32x4 IRr[2] = {zero, zero}, IRi[2] = {zero, zero};
    #pragma unroll
    for (int s = 0; s < 2; ++s) {
        int ko = s * 32 + quad * 8;
        #pragma unroll
        for (int t2 = 0; t2 < 2; ++t2) {
            int qrow = (t2 * 16 + l15) * 72 + ko;
            half8 fqr = *(const half8*)&Lqr[qrow];
            half8 fqi = *(const half8*)&Lqi[qrow];
            IRr[t2] = __builtin_amdgcn_mfma_f32_16x16x32_f16(fSr[s],  fqr, IRr[t2], 0, 0, 0);
            IRr[t2] = __builtin_amdgcn_mfma_f32_16x16x32_f16(fSiN[s], fqi, IRr[t2], 0, 0, 0);
            IRi[t2] = __builtin_amdgcn_mfma_f32_16x16x32_f16(fSr[s],  fqi, IRi[t2], 0, 0, 0);
            IRi[t2] = __builtin_amdgcn_mfma_f32_16x16x32_f16(fSi[s],  fqr, IRi[t2], 0, 0, 0);
        }
    }
    // ---- mask + decay -> Wr_/Wi_; den partials ----
    #pragma unroll
    for (int reg = 0; reg < 4; ++reg) {
        int t = th * 16 + quad * 4 + reg;
        int u = uh * 16 + l15;
        float wr = 0.f, wi = 0.f, dd = 0.f;
        if (u <= t) {
            float2 p = s_apow[t - u];
            wr = p.x * Ar[reg] - p.y * Ai[reg];
            wi = p.x * Ai[reg] + p.y * Ar[reg];
            dd = s_azpow[t - u] * Dn[reg];
        }
        Wr_[t * 40 + u] = (_Float16)wr;
        Wi_[t * 40 + u] = (_Float16)wi;
        dd += __shfl_xor(dd, 1); dd += __shfl_xor(dd, 2);
        dd += __shfl_xor(dd, 4); dd += __shfl_xor(dd, 8);
        if (l15 == 0) sDenP[uh][t] = dd;
    }
    __syncthreads();

    if (tid < 32) {
        float den = sDenP[0][tid] + sDenP[1][tid] + s_azpow[tid + 1] * sZdot[tid];
        sDinv[tid] = 1.f / (den + EPS_F);
    }

    // ---- phase 2: intra = vT @ sW^T ----
    f32x4 NRr[2] = {zero, zero}, NRi[2] = {zero, zero};
    {
        const int vrow = (w * 16 + l15) * 40 + quad * 8;
        half8 fvr = *(const half8*)&Vtr[vrow];
        half8 fvi = *(const half8*)&Vti[vrow];
        half8 fviN = neg8r(fvi);
        #pragma unroll
        for (int t2 = 0; t2 < 2; ++t2) {
            int trow = (t2 * 16 + l15) * 40 + quad * 8;
            half8 fWr = *(const half8*)&Wr_[trow];
            half8 fWi = *(const half8*)&Wi_[trow];
            NRr[t2] = __builtin_amdgcn_mfma_f32_16x16x32_f16(fvr,  fWr, NRr[t2], 0, 0, 0);
            NRr[t2] = __builtin_amdgcn_mfma_f32_16x16x32_f16(fviN, fWi, NRr[t2], 0, 0, 0);
            NRi[t2] = __builtin_amdgcn_mfma_f32_16x16x32_f16(fvr,  fWi, NRi[t2], 0, 0, 0);
            NRi[t2] = __builtin_amdgcn_mfma_f32_16x16x32_f16(fvi,  fWr, NRi[t2], 0, 0, 0);
        }
    }
    __syncthreads();

    // ---- epilogue ----
    #pragma unroll
    for (int t2 = 0; t2 < 2; ++t2) {
        int t = t2 * 16 + l15;
        float2 fac = s_apow[t + 1];
        float dinv = sDinv[t];
        half4 hre, him;
        #pragma unroll
        for (int reg = 0; reg < 4; ++reg) {
            float rx = NRr[t2][reg] + fac.x * IRr[t2][reg] - fac.y * IRi[t2][reg];
            float ry = NRi[t2][reg] + fac.x * IRi[t2][reg] + fac.y * IRr[t2][reg];
            hre[reg] = (_Float16)(rx * dinv);
            him[reg] = (_Float16)(ry * dinv);
        }
        int vd0 = w * 16 + quad * 4;
        _Float16* orow = Y2h + (size_t)(c * CL + t) * 1024 + h * HDD;
        *(half4*)&orow[vd0]       = hre;
        *(half4*)&orow[512 + vd0] = him;
    }
}

// ---------------------------------------------------------------------------
extern "C" void kernel_launch(void* const* d_in, const int* in_sizes, int n_in,
                              void* d_out, int out_size, void* d_ws, size_t ws_size,
                              hipStream_t stream)
{
    const float* x    = (const float*)d_in[0];
    const float* q_wr = (const float*)d_in[1];
    const float* q_wi = (const float*)d_in[2];
    const float* q_br = (const float*)d_in[3];
    const float* q_bi = (const float*)d_in[4];
    const float* k_wr = (const float*)d_in[5];
    const float* k_wi = (const float*)d_in[6];
    const float* k_br = (const float*)d_in[7];
    const float* k_bi = (const float*)d_in[8];
    const float* v_wr = (const float*)d_in[9];
    const float* v_wi = (const float*)d_in[10];
    const float* v_br = (const float*)d_in[11];
    const float* v_bi = (const float*)d_in[12];
    const float* o_wr = (const float*)d_in[13];
    const float* o_wi = (const float*)d_in[14];
    const float* o_br = (const float*)d_in[15];
    const float* o_bi = (const float*)d_in[16];
    const float* log_decay_s = (const float*)d_in[17];
    const float* log_decay_z = (const float*)d_in[18];
    const float* phase       = (const float*)d_in[19];

    float* ws = (float*)d_ws;
    float* Zcf  = ws;                          // 32768 f
    float* ball = ws + 32768;                  // 3072 f
    float* b2a  = ws + 35840;                  // 1024 f
    _Float16* WTa = (_Float16*)(ws + 36864);   // 1572864 h
    _Float16* W2T = WTa + 1572864;             // 1048576 h
    _Float16* Y2h = W2T + 1048576;             // 2097152 h
    _Float16* PL  = Y2h + 2097152;             // 8 x 1048576 h
    unsigned int* ScU = (unsigned int*)(PL + 8388608);  // 2097152 u32

    int out_mode = (out_size == 2048 * 1024) ? 1 : 0;

    prep_kernel<<<656, 256, 0, stream>>>(q_wr, q_wi, k_wr, k_wi, v_wr, v_wi,
                                         o_wr, o_wi, q_br, q_bi, k_br, k_bi,
                                         v_br, v_bi, o_br, o_bi,
                                         WTa, W2T, ball, b2a);

    gemm_qkv_kernel<<<dim3(24, 32), 256, 0, stream>>>(x, WTa, ball, PL);

    chunkstate_kernel<<<512, 256, 0, stream>>>(PL, log_decay_s, log_decay_z, phase,
                                               ScU, Zcf);

    chunkscan_kernel<<<130, 256, 0, stream>>>(log_decay_s, log_decay_z, phase, ScU, Zcf);

    chunkout_kernel<<<512, 256, 0, stream>>>(PL, ScU, Zcf, log_decay_s, log_decay_z,
                                             phase, Y2h);

    gemm_f16_kernel<<<dim3(8, 32), 256, 0, stream>>>(Y2h, W2T, b2a, (float*)d_out,
                                                     1024, out_mode);
}

// Round 14
// 63.729 us; speedup vs baseline: 1.1026x; 1.0277x over previous
//
#include <hip/hip_runtime.h>
#include <math.h>

#define TT 2048
#define NH 8
#define HDD 64
#define CL 32          // chunk length
#define NC 64          // number of chunks
#define EPS_F 1e-8f

typedef __attribute__((ext_vector_type(8))) _Float16 half8;
typedef __attribute__((ext_vector_type(4))) _Float16 half4;
typedef __attribute__((ext_vector_type(4))) float    f32x4;

__device__ __forceinline__ unsigned int pack2h(float a, float b) {
    union { _Float16 h[2]; unsigned int u; } z;
    z.h[0] = (_Float16)a; z.h[1] = (_Float16)b; return z.u;
}
__device__ __forceinline__ float2 unpack2h(unsigned int w) {
    union { unsigned int u; _Float16 h[2]; } z; z.u = w;
    return make_float2((float)z.h[0], (float)z.h[1]);
}
// register-level negate: XOR fp16 sign bits
__device__ __forceinline__ half8 neg8r(half8 v) {
    union { half8 h; unsigned int u[4]; } z; z.h = v;
    #pragma unroll
    for (int i = 0; i < 4; ++i) z.u[i] ^= 0x80008000u;
    return z.h;
}
__device__ __forceinline__ half8 cvt8f(float4 a, float4 b) {
    half8 r;
    r[0]=(_Float16)a.x; r[1]=(_Float16)a.y; r[2]=(_Float16)a.z; r[3]=(_Float16)a.w;
    r[4]=(_Float16)b.x; r[5]=(_Float16)b.y; r[6]=(_Float16)b.z; r[7]=(_Float16)b.w;
    return r;
}

// ---------------------------------------------------------------------------
// prep: fused wconv (blocks 0..383) + w2prep (384..639) + biasprep (640..655)
// ---------------------------------------------------------------------------
__global__ __launch_bounds__(256) void prep_kernel(
    const float* __restrict__ q_wr, const float* __restrict__ q_wi,
    const float* __restrict__ k_wr, const float* __restrict__ k_wi,
    const float* __restrict__ v_wr, const float* __restrict__ v_wi,
    const float* __restrict__ o_wr, const float* __restrict__ o_wi,
    const float* __restrict__ bq_r, const float* __restrict__ bq_i,
    const float* __restrict__ bk_r, const float* __restrict__ bk_i,
    const float* __restrict__ bv_r, const float* __restrict__ bv_i,
    const float* __restrict__ o_br, const float* __restrict__ o_bi,
    _Float16* __restrict__ WT, _Float16* __restrict__ W2T,
    float* __restrict__ ball, float* __restrict__ b2a)
{
    __shared__ float tile[64][65];
    const int bid = blockIdx.x, tid = threadIdx.x;
    if (bid < 384) {
        const int z = bid >> 6, t = bid & 63;       // z in 0..5
        const int k0 = (t >> 3) * 64, n0 = (t & 7) * 64;
        const int g = z >> 1, p = z & 1;
        const float* W;
        switch (z) {
          case 0: W = q_wr; break;
          case 1: W = q_wi; break;
          case 2: W = k_wr; break;
          case 3: W = k_wi; break;
          case 4: W = v_wr; break;
          default: W = v_wi; break;                 // z == 5
        }
        #pragma unroll
        for (int it = 0; it < 16; ++it) {
            int idx = it * 256 + tid;
            tile[idx >> 6][idx & 63] = W[(size_t)(k0 + (idx >> 6)) * 512 + n0 + (idx & 63)];
        }
        __syncthreads();
        #pragma unroll
        for (int it = 0; it < 16; ++it) {
            int idx = it * 256 + tid;
            int nr = idx >> 6, kc = idx & 63;
            int n = n0 + nr;
            int R = g * 1024 + ((n >> 4) << 5) + p * 16 + (n & 15);
            WT[(size_t)R * 512 + k0 + kc] = (_Float16)tile[kc][nr];
        }
    } else if (bid < 640) {
        const int t = bid - 384;
        const int i0 = (t >> 4) * 64, j0 = (t & 15) * 64;
        const float* src; float sgn; int io, jo;
        if (i0 < 512) {
            if (j0 < 512) { src = o_wr; sgn = 1.f;  io = i0; jo = j0; }
            else          { src = o_wi; sgn = 1.f;  io = i0; jo = j0 - 512; }
        } else {
            if (j0 < 512) { src = o_wi; sgn = -1.f; io = i0 - 512; jo = j0; }
            else          { src = o_wr; sgn = 1.f;  io = i0 - 512; jo = j0 - 512; }
        }
        #pragma unroll
        for (int it = 0; it < 16; ++it) {
            int idx = it * 256 + tid;
            tile[idx >> 6][idx & 63] = sgn * src[(size_t)(io + (idx >> 6)) * 512 + jo + (idx & 63)];
        }
        __syncthreads();
        #pragma unroll
        for (int it = 0; it < 16; ++it) {
            int idx = it * 256 + tid;
            int nr = idx >> 6, kc = idx & 63;
            W2T[(size_t)(j0 + nr) * 1024 + i0 + kc] = (_Float16)tile[kc][nr];
        }
    } else {
        int idx = (bid - 640) * 256 + tid;   // 0..4095
        if (idx < 3072) {
            int g = idx >> 10, wq = idx & 1023;
            int p = (wq >> 4) & 1;
            int n = ((wq >> 5) << 4) | (wq & 15);
            float v;
            switch (g * 2 + p) {
              case 0: v = bq_r[n]; break;
              case 1: v = bq_i[n]; break;
              case 2: v = bk_r[n]; break;
              case 3: v = bk_i[n]; break;
              case 4: v = bv_r[n]; break;
              default: v = bv_i[n]; break;
            }
            ball[idx] = v;
        } else {
            int j = idx - 3072;
            b2a[j] = (j < 512) ? o_br[j] : o_bi[j - 512];
        }
    }
}

// ---------------------------------------------------------------------------
// GEMM1 fused w/ feature epilogue. BM=64, double-buffered LDS, 1 barrier/step.
// grid (24 n-tiles, 32 m-tiles)
// ---------------------------------------------------------------------------
__global__ __launch_bounds__(256) void gemm_qkv_kernel(
    const float* __restrict__ X,
    const _Float16* __restrict__ BT,
    const float* __restrict__ ball,
    _Float16* __restrict__ PL)
{
    __shared__ _Float16 sA[2][64 * 32];
    __shared__ _Float16 sB[2][128 * 32];
    const int tid = threadIdx.x;
    const int bx = blockIdx.x, by = blockIdx.y;
    const int m0 = by * 64, R0 = bx * 128;
    const int g = bx >> 3;
    const int nb = (bx & 7) * 64;
    const int lane = tid & 63;
    const int w = tid >> 6, wm = w >> 1, wn = w & 1;
    const int quad = lane >> 4, l15 = lane & 15;

    f32x4 acc[2][4];
    #pragma unroll
    for (int i = 0; i < 2; ++i)
        #pragma unroll
        for (int j = 0; j < 4; ++j) { f32x4 z = {0.f, 0.f, 0.f, 0.f}; acc[i][j] = z; }

    const int rA0 = tid >> 2, sq = tid & 3;
    const float* gA0 = X + (size_t)(m0 + rA0) * 512 + (sq ^ ((rA0 >> 1) & 3)) * 8;
    const int aofs = rA0 * 32 + sq * 8;

    const int rB0 = tid >> 2, rB1 = rB0 + 64;
    const _Float16* gB0 = BT + (size_t)(R0 + rB0) * 512 + (sq ^ ((rB0 >> 1) & 3)) * 8;
    const _Float16* gB1 = BT + (size_t)(R0 + rB1) * 512 + (sq ^ ((rB1 >> 1) & 3)) * 8;
    const int bofs0 = rB0 * 32 + sq * 8;
    const int bofs1 = rB1 * 32 + sq * 8;

    const int arow = wm * 32 + l15;
    const int brow = wn * 64 + l15;

    float4 a00 = *(const float4*)gA0, a01 = *(const float4*)(gA0 + 4);
    float4 pb0 = *(const float4*)gB0, pb1 = *(const float4*)gB1;
    *(half8*)&sA[0][aofs]  = cvt8f(a00, a01);
    *(float4*)&sB[0][bofs0] = pb0;
    *(float4*)&sB[0][bofs1] = pb1;
    a00 = *(const float4*)(gA0 + 32); a01 = *(const float4*)(gA0 + 36);
    pb0 = *(const float4*)(gB0 + 32); pb1 = *(const float4*)(gB1 + 32);
    __syncthreads();

    for (int ks = 0; ks < 16; ++ks) {
        const int cur = ks & 1;
        half8 af[2], bf[4];
        #pragma unroll
        for (int mt = 0; mt < 2; ++mt) {
            int r = arow + mt * 16;
            int qp = quad ^ ((r >> 1) & 3);
            af[mt] = *(half8*)&sA[cur][r * 32 + qp * 8];
        }
        #pragma unroll
        for (int nt = 0; nt < 4; ++nt) {
            int r = brow + nt * 16;
            int qp = quad ^ ((r >> 1) & 3);
            bf[nt] = *(half8*)&sB[cur][r * 32 + qp * 8];
        }
        #pragma unroll
        for (int mt = 0; mt < 2; ++mt)
            #pragma unroll
            for (int nt = 0; nt < 4; ++nt)
                acc[mt][nt] = __builtin_amdgcn_mfma_f32_16x16x32_f16(af[mt], bf[nt], acc[mt][nt], 0, 0, 0);
        if (ks + 1 < 16) {
            *(half8*)&sA[cur ^ 1][aofs]  = cvt8f(a00, a01);
            *(float4*)&sB[cur ^ 1][bofs0] = pb0;
            *(float4*)&sB[cur ^ 1][bofs1] = pb1;
            if (ks + 2 < 16) {
                int ko = (ks + 2) << 5;
                a00 = *(const float4*)(gA0 + ko); a01 = *(const float4*)(gA0 + ko + 4);
                pb0 = *(const float4*)(gB0 + ko); pb1 = *(const float4*)(gB1 + ko);
            }
        }
        __syncthreads();
    }

    _Float16* qfr = PL;
    _Float16* qfi = PL + 1048576;
    _Float16* gqp = PL + 2097152;
    _Float16* kkr = PL + 3145728;
    _Float16* kki = PL + 4194304;
    _Float16* gkp = PL + 5242880;
    _Float16* vrp = PL + 6291456;
    _Float16* vip = PL + 7340032;

    const int crow0 = m0 + wm * 32 + quad * 4;
    #pragma unroll
    for (int j = 0; j < 2; ++j) {
        int col = nb + wn * 32 + j * 16 + l15;
        float bre = ball[R0 + wn * 64 + j * 32 + l15];
        float bim = ball[R0 + wn * 64 + j * 32 + 16 + l15];
        #pragma unroll
        for (int mt = 0; mt < 2; ++mt) {
            #pragma unroll
            for (int reg = 0; reg < 4; ++reg) {
                int row = crow0 + mt * 16 + reg;
                size_t ofs = (size_t)row * 512 + col;
                float xr = acc[mt][2 * j][reg] + bre;
                float xi = acc[mt][2 * j + 1][reg] + bim;
                if (g == 0) {
                    float gv = sqrtf(xr * xr + xi * xi);
                    float f = gv / (gv + EPS_F);
                    qfr[ofs] = (_Float16)(xr * f);
                    qfi[ofs] = (_Float16)(xi * f);
                    gqp[ofs] = (_Float16)gv;
                } else if (g == 1) {
                    float gv = sqrtf(xr * xr + xi * xi);
                    float f = gv / (gv + EPS_F);
                    kkr[ofs] = (_Float16)(xr * f);
                    kki[ofs] = (_Float16)(-xi * f);   // conj
                    gkp[ofs] = (_Float16)gv;
                } else {
                    vrp[ofs] = (_Float16)xr;
                    vip[ofs] = (_Float16)xi;
                }
            }
        }
    }
}

// ---------------------------------------------------------------------------
// GEMM2: out = Y2h @ W2T^T + b2a. BM=64, double-buffered, 1 barrier/step.
// ---------------------------------------------------------------------------
__global__ __launch_bounds__(256) void gemm_f16_kernel(
    const _Float16* __restrict__ A,
    const _Float16* __restrict__ BT,
    const float* __restrict__ bias,
    float* __restrict__ C,
    int K, int ldc, int wmode)
{
    __shared__ _Float16 sA[2][64 * 32];
    __shared__ _Float16 sB[2][128 * 32];
    const int tid = threadIdx.x;
    const int m0 = blockIdx.y * 64, n0 = blockIdx.x * 128;
    const int lane = tid & 63;
    const int w = tid >> 6, wm = w >> 1, wn = w & 1;
    const int quad = lane >> 4, l15 = lane & 15;

    f32x4 acc[2][4];
    #pragma unroll
    for (int i = 0; i < 2; ++i)
        #pragma unroll
        for (int j = 0; j < 4; ++j) { f32x4 z = {0.f, 0.f, 0.f, 0.f}; acc[i][j] = z; }

    const int rA0 = tid >> 2, sq = tid & 3;
    const _Float16* gA0 = A + (size_t)(m0 + rA0) * K + (sq ^ ((rA0 >> 1) & 3)) * 8;
    const int aofs = rA0 * 32 + sq * 8;

    const int rB0 = tid >> 2, rB1 = rB0 + 64;
    const _Float16* gB0 = BT + (size_t)(n0 + rB0) * K + (sq ^ ((rB0 >> 1) & 3)) * 8;
    const _Float16* gB1 = BT + (size_t)(n0 + rB1) * K + (sq ^ ((rB1 >> 1) & 3)) * 8;
    const int bofs0 = rB0 * 32 + sq * 8;
    const int bofs1 = rB1 * 32 + sq * 8;

    const int arow = wm * 32 + l15;
    const int brow = wn * 64 + l15;
    const int nsteps = K >> 5;

    float4 pa0 = *(const float4*)gA0;
    float4 pb0 = *(const float4*)gB0, pb1 = *(const float4*)gB1;
    *(float4*)&sA[0][aofs]  = pa0;
    *(float4*)&sB[0][bofs0] = pb0;
    *(float4*)&sB[0][bofs1] = pb1;
    if (nsteps > 1) {
        pa0 = *(const float4*)(gA0 + 32);
        pb0 = *(const float4*)(gB0 + 32); pb1 = *(const float4*)(gB1 + 32);
    }
    __syncthreads();

    for (int ks = 0; ks < nsteps; ++ks) {
        const int cur = ks & 1;
        half8 af[2], bf[4];
        #pragma unroll
        for (int mt = 0; mt < 2; ++mt) {
            int r = arow + mt * 16;
            int qp = quad ^ ((r >> 1) & 3);
            af[mt] = *(half8*)&sA[cur][r * 32 + qp * 8];
        }
        #pragma unroll
        for (int nt = 0; nt < 4; ++nt) {
            int r = brow + nt * 16;
            int qp = quad ^ ((r >> 1) & 3);
            bf[nt] = *(half8*)&sB[cur][r * 32 + qp * 8];
        }
        #pragma unroll
        for (int mt = 0; mt < 2; ++mt)
            #pragma unroll
            for (int nt = 0; nt < 4; ++nt)
                acc[mt][nt] = __builtin_amdgcn_mfma_f32_16x16x32_f16(af[mt], bf[nt], acc[mt][nt], 0, 0, 0);
        if (ks + 1 < nsteps) {
            *(float4*)&sA[cur ^ 1][aofs]  = pa0;
            *(float4*)&sB[cur ^ 1][bofs0] = pb0;
            *(float4*)&sB[cur ^ 1][bofs1] = pb1;
            if (ks + 2 < nsteps) {
                int ko = (ks + 2) << 5;
                pa0 = *(const float4*)(gA0 + ko);
                pb0 = *(const float4*)(gB0 + ko); pb1 = *(const float4*)(gB1 + ko);
            }
        }
        __syncthreads();
    }

    const int crow0 = m0 + wm * 32 + quad * 4;
    const int ccol0 = n0 + wn * 64 + l15;
    #pragma unroll
    for (int mt = 0; mt < 2; ++mt) {
        #pragma unroll
        for (int nt = 0; nt < 4; ++nt) {
            int col = ccol0 + nt * 16;
            float b = bias[col];
            #pragma unroll
            for (int rg = 0; rg < 4; ++rg) {
                int row = crow0 + mt * 16 + rg;
                float val = acc[mt][nt][rg] + b;
                if (wmode == 0) {
                    C[(size_t)row * ldc + col] = val;
                } else {
                    int off = (col < 512) ? (row * 1024 + 2 * col) : (row * 1024 + 2 * (col - 512) + 1);
                    C[off] = val;
                }
            }
        }
    }
}

// ---------------------------------------------------------------------------
// chunkstate: MFMA, reads fp16 planes, writes Sc packed half2 (uint).
// ---------------------------------------------------------------------------
__global__ __launch_bounds__(256) void chunkstate_kernel(
    const _Float16* __restrict__ PL,
    const float* __restrict__ lgs, const float* __restrict__ lgz,
    const float* __restrict__ phs,
    unsigned int* __restrict__ ScU, float* __restrict__ Zc)
{
    __shared__ _Float16 wvTr[64 * 40], wvTi[64 * 40];      // [vd][u]
    __shared__ _Float16 kkTr[64 * 40], kkTi[64 * 40];      // [k][u]
    __shared__ float    Lgkz[32 * 65];                     // [u][k]

    const int tid = threadIdx.x;
    const int c = blockIdx.x & 63, h = blockIdx.x >> 6;

    float xs = lgs[h];
    float sps = fmaxf(xs, 0.f) + log1pf(expf(-fabsf(xs)));
    float ph = phs[h];
    float xz = lgz[h];
    float spz = fmaxf(xz, 0.f) + log1pf(expf(-fabsf(xz)));

    const _Float16* kkrP = PL + 3145728;
    const _Float16* kkiP = PL + 4194304;
    const _Float16* gkpP = PL + 5242880;
    const _Float16* vrP  = PL + 6291456;
    const _Float16* viP  = PL + 7340032;

    {
        const int u = tid >> 3, ks = (tid & 7) << 3;
        const size_t rofs = (size_t)(c * CL + u) * 512 + h * HDD + ks;
        half8 kr8 = *(const half8*)&kkrP[rofs];
        half8 ki8 = *(const half8*)&kkiP[rofs];
        half8 gk8 = *(const half8*)&gkpP[rofs];
        half8 vr8 = *(const half8*)&vrP[rofs];
        half8 vi8 = *(const half8*)&viP[rofs];
        float e = (float)(CL - 1 - u);
        float r = expf(-sps * e);
        float wAr = r * cosf(ph * e), wAi = r * sinf(ph * e);
        float wz = expf(-spz * e);
        #pragma unroll
        for (int j = 0; j < 8; ++j) {
            int kcol = ks + j;
            kkTr[kcol * 40 + u] = kr8[j];
            kkTi[kcol * 40 + u] = ki8[j];
            float vre = (float)vr8[j], vim = (float)vi8[j];
            wvTr[kcol * 40 + u] = (_Float16)(wAr * vre - wAi * vim);
            wvTi[kcol * 40 + u] = (_Float16)(wAr * vim + wAi * vre);
            Lgkz[u * 65 + kcol] = wz * (float)gk8[j];
        }
    }
    __syncthreads();

    const int w = tid >> 6, lane = tid & 63;
    const int quad = lane >> 4, l15 = lane & 15;
    const int arow = (w * 16 + l15) * 40 + quad * 8;
    half8 fvr = *(const half8*)&wvTr[arow];
    half8 fvi = *(const half8*)&wvTi[arow];
    unsigned int* out = ScU + ((size_t)(c * NH + h) << 12);
    #pragma unroll
    for (int kq = 0; kq < 4; ++kq) {
        int brow = (kq * 16 + l15) * 40 + quad * 8;
        half8 fkr  = *(const half8*)&kkTr[brow];
        half8 fki  = *(const half8*)&kkTi[brow];
        half8 fkiN = neg8r(fki);
        f32x4 Cr = {0.f, 0.f, 0.f, 0.f}, Ci = {0.f, 0.f, 0.f, 0.f};
        Cr = __builtin_amdgcn_mfma_f32_16x16x32_f16(fvr, fkr,  Cr, 0, 0, 0);
        Cr = __builtin_amdgcn_mfma_f32_16x16x32_f16(fvi, fkiN, Cr, 0, 0, 0);
        Ci = __builtin_amdgcn_mfma_f32_16x16x32_f16(fvr, fki,  Ci, 0, 0, 0);
        Ci = __builtin_amdgcn_mfma_f32_16x16x32_f16(fvi, fkr,  Ci, 0, 0, 0);
        #pragma unroll
        for (int reg = 0; reg < 4; ++reg) {
            int vd = w * 16 + quad * 4 + reg;
            out[vd * 64 + kq * 16 + l15] = pack2h(Cr[reg], Ci[reg]);
        }
    }
    if (tid < 64) {
        float z = 0.f;
        #pragma unroll
        for (int uu = 0; uu < 32; ++uu) z += Lgkz[uu * 65 + tid];
        Zc[(c * NH + h) * 64 + tid] = z;
    }
}

// ---------------------------------------------------------------------------
// chunkscan: exclusive prefix over chunks, packed half2 state,
// software-pipelined batch-8 loads.
// ---------------------------------------------------------------------------
__global__ __launch_bounds__(256) void chunkscan_kernel(
    const float* __restrict__ lgs, const float* __restrict__ lgz,
    const float* __restrict__ phs,
    unsigned int* __restrict__ ScU, float* __restrict__ Zc)
{
    const int bid = blockIdx.x, tid = threadIdx.x;
    if (bid < 128) {
        const int idx = bid * 256 + tid;
        const int h = idx >> 12, e = idx & 4095;
        float xs = lgs[h];
        float sps = fmaxf(xs, 0.f) + log1pf(expf(-fabsf(xs)));
        float ph = phs[h];
        float r = expf(-sps * (float)CL);
        float aLr = r * cosf(ph * (float)CL), aLi = r * sinf(ph * (float)CL);
        unsigned int* p = ScU + (size_t)h * 4096 + e;
        float pr = 0.f, pi = 0.f;
        unsigned int vcur[8], vnext[8];
        #pragma unroll
        for (int j = 0; j < 8; ++j) vcur[j] = p[(size_t)j * 32768];
        #pragma unroll
        for (int cb = 0; cb < 8; ++cb) {
            if (cb + 1 < 8) {
                #pragma unroll
                for (int j = 0; j < 8; ++j)
                    vnext[j] = p[(size_t)(((cb + 1) << 3) + j) * 32768];
            }
            #pragma unroll
            for (int j = 0; j < 8; ++j) {
                float2 tmp = unpack2h(vcur[j]);
                p[(size_t)((cb << 3) + j) * 32768] = pack2h(pr, pi);
                float nr = aLr * pr - aLi * pi + tmp.x;
                float ni = aLr * pi + aLi * pr + tmp.y;
                pr = nr; pi = ni;
            }
            #pragma unroll
            for (int j = 0; j < 8; ++j) vcur[j] = vnext[j];
        }
    } else {
        const int idx = (bid - 128) * 256 + tid;
        const int h = idx >> 6, k = idx & 63;
        float xz = lgz[h];
        float spz = fmaxf(xz, 0.f) + log1pf(expf(-fabsf(xz)));
        float azL = expf(-spz * (float)CL);
        float* p = Zc + h * 64 + k;
        float prev = 0.f;
        float vcur[8], vnext[8];
        #pragma unroll
        for (int j = 0; j < 8; ++j) vcur[j] = p[(size_t)j * 512];
        #pragma unroll
        for (int cb = 0; cb < 8; ++cb) {
            if (cb + 1 < 8) {
                #pragma unroll
                for (int j = 0; j < 8; ++j)
                    vnext[j] = p[(size_t)(((cb + 1) << 3) + j) * 512];
            }
            #pragma unroll
            for (int j = 0; j < 8; ++j) {
                float tmp = vcur[j];
                p[(size_t)((cb << 3) + j) * 512] = prev;
                prev = azL * prev + tmp;
            }
            #pragma unroll
            for (int j = 0; j < 8; ++j) vcur[j] = vnext[j];
        }
    }
}

// ---------------------------------------------------------------------------
// chunkout v4: Sp fragments loaded directly from global into registers;
// fp16 negations in registers; LDS ~44KB.
// ---------------------------------------------------------------------------
__global__ __launch_bounds__(256) void chunkout_kernel(
    const _Float16* __restrict__ PL,
    const unsigned int* __restrict__ SpU, const float* __restrict__ Zp,
    const float* __restrict__ lgs, const float* __restrict__ lgz,
    const float* __restrict__ phs,
    _Float16* __restrict__ Y2h)
{
    __shared__ _Float16 Lqr[32 * 72], Lqi[32 * 72];   // [t][k]
    __shared__ _Float16 Lkr[32 * 72], Lki[32 * 72];   // [u][k]
    __shared__ _Float16 Lgq[32 * 72], Lgk[32 * 72];
    __shared__ _Float16 Vtr[64 * 40], Vti[64 * 40];   // [vd][u]
    __shared__ _Float16 Wr_[32 * 40], Wi_[32 * 40];   // [t][u]
    __shared__ float  sDenP[2][32], sZdot[32], sDinv[32], sZp[64];
    __shared__ float2 s_apow[CL + 1];
    __shared__ float  s_azpow[CL + 1];

    const int tid = threadIdx.x;
    const int c = blockIdx.x & 63, h = blockIdx.x >> 6;
    const int w = tid >> 6, lane = tid & 63;
    const int quad = lane >> 4, l15 = lane & 15;

    // ---- Sp fragment prefetch (global -> regs), overlaps staging ----
    uint4 spv[4];
    {
        const unsigned int* bp = SpU + ((size_t)(c * NH + h) << 12) + (w * 16 + l15) * 64;
        #pragma unroll
        for (int s = 0; s < 2; ++s) {
            spv[s * 2]     = *(const uint4*)(bp + s * 32 + quad * 8);
            spv[s * 2 + 1] = *(const uint4*)(bp + s * 32 + quad * 8 + 4);
        }
    }

    if (tid <= CL) {
        float xs = lgs[h];
        float sps = fmaxf(xs, 0.f) + log1pf(expf(-fabsf(xs)));
        float ph = phs[h];
        float r = expf(-sps * (float)tid);
        s_apow[tid] = make_float2(r * cosf(ph * (float)tid), r * sinf(ph * (float)tid));
        float xz = lgz[h];
        float spz = fmaxf(xz, 0.f) + log1pf(expf(-fabsf(xz)));
        s_azpow[tid] = expf(-spz * (float)tid);
    }
    if (tid < 64) sZp[tid] = Zp[(c * NH + h) * 64 + tid];

    const _Float16* qfrP = PL;
    const _Float16* qfiP = PL + 1048576;
    const _Float16* gqpP = PL + 2097152;
    const _Float16* kkrP = PL + 3145728;
    const _Float16* kkiP = PL + 4194304;
    const _Float16* gkpP = PL + 5242880;
    const _Float16* vrP  = PL + 6291456;
    const _Float16* viP  = PL + 7340032;

    {
        const int u = tid >> 3, ks = (tid & 7) << 3;
        const size_t rofs = (size_t)(c * CL + u) * 512 + h * HDD + ks;
        half8 qr  = *(const half8*)&qfrP[rofs];
        half8 qi  = *(const half8*)&qfiP[rofs];
        half8 g8q = *(const half8*)&gqpP[rofs];
        half8 kr  = *(const half8*)&kkrP[rofs];
        half8 ki  = *(const half8*)&kkiP[rofs];
        half8 g8k = *(const half8*)&gkpP[rofs];
        half8 vr8 = *(const half8*)&vrP[rofs];
        half8 vi8 = *(const half8*)&viP[rofs];
        int ofs = u * 72 + ks;
        *(half8*)&Lqr[ofs] = qr;  *(half8*)&Lqi[ofs] = qi;
        *(half8*)&Lkr[ofs] = kr;  *(half8*)&Lki[ofs] = ki;
        *(half8*)&Lgq[ofs] = g8q; *(half8*)&Lgk[ofs] = g8k;
        #pragma unroll
        for (int j = 0; j < 8; ++j) {
            Vtr[(ks + j) * 40 + u] = vr8[j];
            Vti[(ks + j) * 40 + u] = vi8[j];
        }
    }
    __syncthreads();

    // ---- zdot[t] = Zp . gq[t] ----
    {
        const int t = tid >> 3, k8 = (tid & 7) << 3;
        float z = 0.f;
        #pragma unroll
        for (int j = 0; j < 8; ++j) z += sZp[k8 + j] * (float)Lgq[t * 72 + k8 + j];
        z += __shfl_xor(z, 1); z += __shfl_xor(z, 2); z += __shfl_xor(z, 4);
        if ((tid & 7) == 0) sZdot[t] = z;
    }

    // ---- unpack Sp fragments ----
    half8 fSr[2], fSi[2], fSiN[2];
    #pragma unroll
    for (int s = 0; s < 2; ++s) {
        unsigned int uu[8];
        *(uint4*)&uu[0] = spv[s * 2];
        *(uint4*)&uu[4] = spv[s * 2 + 1];
        #pragma unroll
        for (int j = 0; j < 8; ++j) {
            union { unsigned int u; _Float16 hh[2]; } z; z.u = uu[j];
            fSr[s][j] = z.hh[0]; fSi[s][j] = z.hh[1];
        }
        fSiN[s] = neg8r(fSi[s]);
    }

    const int th = w >> 1, uh = w & 1;
    const f32x4 zero = {0.f, 0.f, 0.f, 0.f};

    // ---- phase 1a: scores + den ----
    f32x4 Ar = zero, Ai = zero, Dn = zero;
    {
        const int qrow = (th * 16 + l15) * 72;
        const int krow = (uh * 16 + l15) * 72;
        #pragma unroll
        for (int s = 0; s < 2; ++s) {
            int ko = s * 32 + quad * 8;
            half8 fqr  = *(const half8*)&Lqr[qrow + ko];
            half8 fqi  = *(const half8*)&Lqi[qrow + ko];
            half8 fkr  = *(const half8*)&Lkr[krow + ko];
            half8 fki  = *(const half8*)&Lki[krow + ko];
            half8 fkiN = neg8r(fki);
            Ar = __builtin_amdgcn_mfma_f32_16x16x32_f16(fqr, fkr,  Ar, 0, 0, 0);
            Ar = __builtin_amdgcn_mfma_f32_16x16x32_f16(fqi, fkiN, Ar, 0, 0, 0);
            Ai = __builtin_amdgcn_mfma_f32_16x16x32_f16(fqr, fki,  Ai, 0, 0, 0);
            Ai = __builtin_amdgcn_mfma_f32_16x16x32_f16(fqi, fkr,  Ai, 0, 0, 0);
            half8 fgq = *(const half8*)&Lgq[qrow + ko];
            half8 fgk = *(const half8*)&Lgk[krow + ko];
            Dn = __builtin_amdgcn_mfma_f32_16x16x32_f16(fgq, fgk, Dn, 0, 0, 0);
        }
    }
    // ---- phase 1b: inter = Sp @ qf ----
    f32x4 IRr[2] = {zero, zero}, IRi[2] = {zero, zero};
    #pragma unroll
    for (int s = 0; s < 2; ++s) {
        int ko = s * 32 + quad * 8;
        #pragma unroll
        for (int t2 = 0; t2 < 2; ++t2) {
            int qrow = (t2 * 16 + l15) * 72 + ko;
            half8 fqr = *(const half8*)&Lqr[qrow];
            half8 fqi = *(const half8*)&Lqi[qrow];
            IRr[t2] = __builtin_amdgcn_mfma_f32_16x16x32_f16(fSr[s],  fqr, IRr[t2], 0, 0, 0);
            IRr[t2] = __builtin_amdgcn_mfma_f32_16x16x32_f16(fSiN[s], fqi, IRr[t2], 0, 0, 0);
            IRi[t2] = __builtin_amdgcn_mfma_f32_16x16x32_f16(fSr[s],  fqi, IRi[t2], 0, 0, 0);
            IRi[t2] = __builtin_amdgcn_mfma_f32_16x16x32_f16(fSi[s],  fqr, IRi[t2], 0, 0, 0);
        }
    }
    // ---- mask + decay -> Wr_/Wi_; den partials ----
    #pragma unroll
    for (int reg = 0; reg < 4; ++reg) {
        int t = th * 16 + quad * 4 + reg;
        int u = uh * 16 + l15;
        float wr = 0.f, wi = 0.f, dd = 0.f;
        if (u <= t) {
            float2 p = s_apow[t - u];
            wr = p.x * Ar[reg] - p.y * Ai[reg];
            wi = p.x * Ai[reg] + p.y * Ar[reg];
            dd = s_azpow[t - u] * Dn[reg];
        }
        Wr_[t * 40 + u] = (_Float16)wr;
        Wi_[t * 40 + u] = (_Float16)wi;
        dd += __shfl_xor(dd, 1); dd += __shfl_xor(dd, 2);
        dd += __shfl_xor(dd, 4); dd += __shfl_xor(dd, 8);
        if (l15 == 0) sDenP[uh][t] = dd;
    }
    __syncthreads();

    if (tid < 32) {
        float den = sDenP[0][tid] + sDenP[1][tid] + s_azpow[tid + 1] * sZdot[tid];
        sDinv[tid] = 1.f / (den + EPS_F);
    }

    // ---- phase 2: intra = vT @ sW^T ----
    f32x4 NRr[2] = {zero, zero}, NRi[2] = {zero, zero};
    {
        const int vrow = (w * 16 + l15) * 40 + quad * 8;
        half8 fvr = *(const half8*)&Vtr[vrow];
        half8 fvi = *(const half8*)&Vti[vrow];
        half8 fviN = neg8r(fvi);
        #pragma unroll
        for (int t2 = 0; t2 < 2; ++t2) {
            int trow = (t2 * 16 + l15) * 40 + quad * 8;
            half8 fWr = *(const half8*)&Wr_[trow];
            half8 fWi = *(const half8*)&Wi_[trow];
            NRr[t2] = __builtin_amdgcn_mfma_f32_16x16x32_f16(fvr,  fWr, NRr[t2], 0, 0, 0);
            NRr[t2] = __builtin_amdgcn_mfma_f32_16x16x32_f16(fviN, fWi, NRr[t2], 0, 0, 0);
            NRi[t2] = __builtin_amdgcn_mfma_f32_16x16x32_f16(fvr,  fWi, NRi[t2], 0, 0, 0);
            NRi[t2] = __builtin_amdgcn_mfma_f32_16x16x32_f16(fvi,  fWr, NRi[t2], 0, 0, 0);
        }
    }
    __syncthreads();

    // ---- epilogue ----
    #pragma unroll
    for (int t2 = 0; t2 < 2; ++t2) {
        int t = t2 * 16 + l15;
        float2 fac = s_apow[t + 1];
        float dinv = sDinv[t];
        half4 hre, him;
        #pragma unroll
        for (int reg = 0; reg < 4; ++reg) {
            float rx = NRr[t2][reg] + fac.x * IRr[t2][reg] - fac.y * IRi[t2][reg];
            float ry = NRi[t2][reg] + fac.x * IRi[t2][reg] + fac.y * IRr[t2][reg];
            hre[reg] = (_Float16)(rx * dinv);
            him[reg] = (_Float16)(ry * dinv);
        }
        int vd0 = w * 16 + quad * 4;
        _Float16* orow = Y2h + (size_t)(c * CL + t) * 1024 + h * HDD;
        *(half4*)&orow[vd0]       = hre;
        *(half4*)&orow[512 + vd0] = him;
    }
}

// ---------------------------------------------------------------------------
extern "C" void kernel_launch(void* const* d_in, const int* in_sizes, int n_in,
                              void* d_out, int out_size, void* d_ws, size_t ws_size,
                              hipStream_t stream)
{
    const float* x    = (const float*)d_in[0];
    const float* q_wr = (const float*)d_in[1];
    const float* q_wi = (const float*)d_in[2];
    const float* q_br = (const float*)d_in[3];
    const float* q_bi = (const float*)d_in[4];
    const float* k_wr = (const float*)d_in[5];
    const float* k_wi = (const float*)d_in[6];
    const float* k_br = (const float*)d_in[7];
    const float* k_bi = (const float*)d_in[8];
    const float* v_wr = (const float*)d_in[9];
    const float* v_wi = (const float*)d_in[10];
    const float* v_br = (const float*)d_in[11];
    const float* v_bi = (const float*)d_in[12];
    const float* o_wr = (const float*)d_in[13];
    const float* o_wi = (const float*)d_in[14];
    const float* o_br = (const float*)d_in[15];
    const float* o_bi = (const float*)d_in[16];
    const float* log_decay_s = (const float*)d_in[17];
    const float* log_decay_z = (const float*)d_in[18];
    const float* phase       = (const float*)d_in[19];

    float* ws = (float*)d_ws;
    float* Zcf  = ws;                          // 32768 f
    float* ball = ws + 32768;                  // 3072 f
    float* b2a  = ws + 35840;                  // 1024 f
    _Float16* WTa = (_Float16*)(ws + 36864);   // 1572864 h
    _Float16* W2T = WTa + 1572864;             // 1048576 h
    _Float16* Y2h = W2T + 1048576;             // 2097152 h
    _Float16* PL  = Y2h + 2097152;             // 8 x 1048576 h
    unsigned int* ScU = (unsigned int*)(PL + 8388608);  // 2097152 u32

    int out_mode = (out_size == 2048 * 1024) ? 1 : 0;

    prep_kernel<<<656, 256, 0, stream>>>(q_wr, q_wi, k_wr, k_wi, v_wr, v_wi,
                                         o_wr, o_wi, q_br, q_bi, k_br, k_bi,
                                         v_br, v_bi, o_br, o_bi,
                                         WTa, W2T, ball, b2a);

    gemm_qkv_kernel<<<dim3(24, 32), 256, 0, stream>>>(x, WTa, ball, PL);

    chunkstate_kernel<<<512, 256, 0, stream>>>(PL, log_decay_s, log_decay_z, phase,
                                               ScU, Zcf);

    chunkscan_kernel<<<130, 256, 0, stream>>>(log_decay_s, log_decay_z, phase, ScU, Zcf);

    chunkout_kernel<<<512, 256, 0, stream>>>(PL, ScU, Zcf, log_decay_s, log_decay_z,
                                             phase, Y2h);

    if (out_mode == 1) {
        gemm_f16_kernel<<<dim3(8, 32), 256, 0, stream>>>(Y2h, W2T, b2a, (float*)d_out,
                                                         1024, 1024, 1);
    } else {
        gemm_f16_kernel<<<dim3(4, 32), 256, 0, stream>>>(Y2h, W2T, b2a, (float*)d_out,
                                                         1024, 512, 0);
    }
}